// Round 9
// baseline (7832.846 us; speedup 1.0000x reference)
//
#include <hip/hip_runtime.h>
#include <hip/hip_bf16.h>

// ============================================================================
// VisionBDHv2 forward, MI355X (gfx950). Round 16.
// R15: 6049us (attn XCD/bL remap: FETCH 79->46MB but dur flat 97us =>
// attn is PURE-LATENCY-bound: grid 384 = 1.5 blk/CU, 74 barrier-drain steps
// with no interleave partner on half the CUs).
// R16: barrier-free attn via direct L2 fragment loads (guide mistake #7:
// don't LDS-stage what L2-fits):
//   - scores: NO LDS. af/bfr loaded straight from qr: one wave-load = 16
//     rows x 64B full cache lines (lanes=rows, lane-groups=k) - perfectly
//     coalesced, no swizzle. Col-tiles merged (A loaded once). 0 barriers
//     (was 32 drain-steps).
//   - PV: B-frags direct from hnT (L2-resident via R15 remap); A from Pl
//     (stride-232, 2-way alias = free). 0 barriers in PV (was 42).
//   - 5 barriers total (softmax + Pl/part visibility). LDS = Pl+part 63KB.
// Everything else identical to R15.
// ============================================================================

typedef short bf16x8 __attribute__((ext_vector_type(8)));
typedef float f32x4 __attribute__((ext_vector_type(4)));
typedef unsigned short u16;

#define LN_EPS 1e-5f
#define SM_SCALE 0.044194173824159216f  /* 1/sqrt(512) */
#define TWO_PI 6.283185307179586f
#define MC 3136                          /* rows per chunk = 16*196 */

typedef __attribute__((address_space(3))) unsigned char* as3p;
typedef const __attribute__((address_space(1))) unsigned char* as1p;

__device__ __forceinline__ void gload16(const u16* g, u16* l) {
    __builtin_amdgcn_global_load_lds((as1p)(const void*)g, (as3p)(void*)l, 16, 0, 0);
}

__device__ __forceinline__ u16 f2bf(float f) {
    __hip_bfloat16 h = __float2bfloat16(f);
    return *reinterpret_cast<u16*>(&h);
}
__device__ __forceinline__ float bf2f(u16 u) {
    return __uint_as_float(((unsigned)u) << 16);
}

// ---------------------------------------------------------------------------
// block reductions (256 threads, 4 waves)
// ---------------------------------------------------------------------------
__device__ __forceinline__ float block_reduce_sum(float v, float* sm) {
    #pragma unroll
    for (int o = 32; o; o >>= 1) v += __shfl_xor(v, o);
    if ((threadIdx.x & 63) == 0) sm[threadIdx.x >> 6] = v;
    __syncthreads();
    float r = sm[0] + sm[1] + sm[2] + sm[3];
    __syncthreads();
    return r;
}

// ---------------------------------------------------------------------------
// GEMM core (R7/R11 gemm_core64, verbatim): BK=64, swizzled, 128x128 tile,
// 4 waves (2x2). LDS [128][64] u16 per operand; physical slot s holds
// logical col-slot s^(row&7). Staged via global_load_lds with pre-swizzled
// global source (linear LDS dest). ds_read applies same XOR. C/D: elem i ->
// row (lane>>4)*4+i, col lane&15.
// ---------------------------------------------------------------------------
__device__ __forceinline__ void gemm_core64(const u16* __restrict__ A, int lda,
                                            const u16* __restrict__ Bt, int ldb,
                                            int ksteps, f32x4 acc[4][4],
                                            u16* lds_a, u16* lds_b) {
    const int tid = threadIdx.x;
    const int lane = tid & 63;
    const int wave = tid >> 6;
    const int wr = (wave >> 1) * 64;
    const int wc = (wave & 1) * 64;
    const int lr = lane & 15;
    const int lg = lane >> 4;            // logical k-slot base (0..3)
    const int rx = lr & 7;               // row&7 for this lane's fragment rows
    const int srow = tid >> 3;           // staging row within 32-row group
    const int gslot = (tid & 7) ^ (srow & 7);  // pre-swizzled global col slot
    const u16* ga = A + (long)srow * lda + gslot * 8;
    const u16* gb = Bt + (long)srow * ldb + gslot * 8;
    u16* la = lds_a + tid * 8;           // linear dest: row srow, slot tid&7
    u16* lb = lds_b + tid * 8;
    for (int k0 = 0; k0 < ksteps; ++k0) {
        __syncthreads();                 // prior iteration's reads done
        #pragma unroll
        for (int j = 0; j < 4; ++j) {    // 32-row groups (row&7 invariant)
            gload16(ga + (long)(j * 32) * lda, la + j * 2048);
            gload16(gb + (long)(j * 32) * ldb, lb + j * 2048);
        }
        ga += 64; gb += 64;
        __syncthreads();                 // drains vmcnt(0) before barrier
        bf16x8 af[2][4], bfr[2][4];
        #pragma unroll
        for (int kk = 0; kk < 2; ++kk) {
            const int ps = ((lg + kk * 4) ^ rx) * 8;   // physical elem offset
            #pragma unroll
            for (int m = 0; m < 4; m++)
                af[kk][m] = *(const bf16x8*)&lds_a[(wr + 16 * m + lr) * 64 + ps];
            #pragma unroll
            for (int n = 0; n < 4; n++)
                bfr[kk][n] = *(const bf16x8*)&lds_b[(wc + 16 * n + lr) * 64 + ps];
        }
        #pragma unroll
        for (int kk = 0; kk < 2; ++kk)
            #pragma unroll
            for (int m = 0; m < 4; m++)
                #pragma unroll
                for (int n = 0; n < 4; n++)
                    acc[m][n] = __builtin_amdgcn_mfma_f32_16x16x32_bf16(
                        af[kk][m], bfr[kk][n], acc[m][n], 0, 0, 0);
    }
}

// merged 32KB LDS: gemm uses [lds_a | lds_b]; epilogue reuses as one tile
// (TU u16[128][128] or TF f32[64][128]).
#define GEMM64_PROLOGUE                                 \
    __shared__ alignas(16) u16 lds_ab[2 * 128 * 64];    \
    u16* lds_a = lds_ab;                                \
    u16* lds_b = lds_ab + 128 * 64;                     \
    f32x4 acc[4][4];                                    \
    _Pragma("unroll")                                   \
    for (int m = 0; m < 4; m++)                         \
        _Pragma("unroll")                               \
        for (int n = 0; n < 4; n++)                     \
            acc[m][n] = (f32x4){0.f, 0.f, 0.f, 0.f};

#define EPI_VARS                                        \
    const int lane = threadIdx.x & 63;                  \
    const int wave = threadIdx.x >> 6;                  \
    const int ewr = (wave >> 1) * 64 + (lane >> 4) * 4; \
    const int ewc = (wave & 1) * 64 + (lane & 15);

// ---------------------------------------------------------------------------
// setup kernels
// ---------------------------------------------------------------------------
__global__ __launch_bounds__(256) void k_pack_patches(const float* __restrict__ x,
                                                      u16* __restrict__ ap) {
    int idx = blockIdx.x * 256 + threadIdx.x;           // < 12544*768
    int r = idx / 768, k = idx - r * 768;
    int b = r / 196, t = r - b * 196;
    int hp = t / 14, wp = t - hp * 14;
    int c = k >> 8, rem = k & 255, p = rem >> 4, q = rem & 15;
    long src = ((long)(b * 3 + c) * 224 + hp * 16 + p) * 224 + wp * 16 + q;
    ap[idx] = f2bf(x[src]);
}

__global__ __launch_bounds__(256) void k_cast(const float* __restrict__ s,
                                              u16* __restrict__ d, int n) {
    int i = blockIdx.x * 256 + threadIdx.x;
    if (i < n) d[i] = f2bf(s[i]);
}

// src (batch, R, C) f32 -> dst (batch, C, R) bf16
__global__ __launch_bounds__(256) void k_transpose_cast(const float* __restrict__ src,
                                                        u16* __restrict__ dst,
                                                        int R, int C) {
    __shared__ float tile[32][33];
    int c0 = blockIdx.x * 32, r0 = blockIdx.y * 32;
    long base = (long)blockIdx.z * R * C;
    int i = threadIdx.x >> 5, j = threadIdx.x & 31;
    #pragma unroll
    for (int p = 0; p < 4; p++) {
        int rr = i + p * 8;
        tile[rr][j] = src[base + (long)(r0 + rr) * C + c0 + j];
    }
    __syncthreads();
    #pragma unroll
    for (int p = 0; p < 4; p++) {
        int rr = i + p * 8;
        dst[base + (long)(c0 + rr) * R + r0 + j] = f2bf(tile[j][rr]);
    }
}

__global__ __launch_bounds__(256) void k_rope_tab(const float* __restrict__ freqs,
                                                  float* __restrict__ tc,
                                                  float* __restrict__ ts) {
    int idx = blockIdx.x * 256 + threadIdx.x;           // < 196*512
    int t = idx >> 9, n = idx & 511;
    float ph = (float)t * freqs[n];
    ph = (ph - floorf(ph)) * TWO_PI;
    tc[idx] = cosf(ph);
    ts[idx] = sinf(ph);
}

// colsum[h][c] = sum_d encv[h][d][c]  (from f32 encv, coalesced in c)
__global__ __launch_bounds__(256) void k_colsum(const float* __restrict__ encv,
                                                float* __restrict__ cs) {
    int h = blockIdx.y, c = blockIdx.x * 256 + threadIdx.x;   // grid (2,12)
    const float* base = encv + (long)h * 768 * 512 + c;
    float a = 0.f;
    for (int d = 0; d < 768; d++) a += base[(long)d * 512];
    cs[h * 512 + c] = a;
}

// ---------------------------------------------------------------------------
// GEMM kernels (R11 core + LDS-bounce epilogues)
// ---------------------------------------------------------------------------
// tokens = patches @ convw^T + bias + pos_embed -> h   (M=12544,K=768,N=768)
__global__ __launch_bounds__(256) void k_gemm_tokens(const u16* __restrict__ ap,
                                                     const u16* __restrict__ bw,
                                                     const float* __restrict__ cb,
                                                     const float* __restrict__ pe,
                                                     float* __restrict__ hout) {
    GEMM64_PROLOGUE
    int row0 = blockIdx.x * 128, col0 = blockIdx.y * 128;
    gemm_core64(ap + (long)row0 * 768, 768, bw + (long)col0 * 768, 768, 12, acc, lds_a, lds_b);
    EPI_VARS
    const int tid = threadIdx.x;
    float* TF = (float*)lds_ab;          // [64][128] f32, two half-passes
    #pragma unroll
    for (int hf = 0; hf < 2; ++hf) {
        __syncthreads();
        if ((ewr >> 6) == hf) {
            #pragma unroll
            for (int m = 0; m < 4; m++)
                #pragma unroll
                for (int n = 0; n < 4; n++)
                    #pragma unroll
                    for (int i = 0; i < 4; i++) {
                        int row = row0 + ewr + 16 * m + i;
                        int col = col0 + ewc + 16 * n;
                        int t = row % 196;
                        TF[(ewr - hf * 64 + 16 * m + i) * 128 + ewc + 16 * n] =
                            acc[m][n][i] + cb[col] + pe[t * 768 + col];
                    }
        }
        __syncthreads();
        #pragma unroll
        for (int q = 0; q < 8; ++q) {
            int chunk = tid + q * 256;   // 64 rows x 32 chunks (16B=4 f32)
            int r = chunk >> 5, c = chunk & 31;
            *(f32x4*)&hout[(long)(row0 + hf * 64 + r) * 768 + col0 + c * 4] =
                *(f32x4*)&TF[r * 128 + c * 4];
        }
    }
}

// chunk: x_sparse = relu(hn@enc); qr = rope(x_sparse)  (M=3136 masked, N=6144)
// xs/qr written HEAD-MAJOR: [(head*16+bL)*196 + t][512]
// R15: rope pass vectorized (TU readback + f32x4 tables + in-reg pair rotate)
__global__ __launch_bounds__(256) void k_gemm_xs(const u16* __restrict__ hnb,
                                                 const u16* __restrict__ enct,
                                                 const float* __restrict__ tc,
                                                 const float* __restrict__ tsn,
                                                 u16* __restrict__ xs,
                                                 u16* __restrict__ qr) {
    GEMM64_PROLOGUE
    // XCD swizzle: grid (25,48) -> 1200 wgs, q=150
    int p = blockIdx.x + 25 * blockIdx.y;
    int w = (p & 7) * 150 + (p >> 3);
    int row0 = (w % 25) * 128, col0 = (w / 25) * 128;
    int head = col0 >> 9, nn0 = col0 & 511;
    gemm_core64(hnb + (long)row0 * 768, 768,
                enct + ((long)head * 512 + nn0) * 768, 768, 12, acc, lds_a, lds_b);
    EPI_VARS
    const int tid = threadIdx.x;
    u16* TU = lds_ab;                    // [128][128] u16
    // ---- pass 1: xs = relu(acc) -> TU -> vector store ----
    __syncthreads();
    #pragma unroll
    for (int m = 0; m < 4; m++)
        #pragma unroll
        for (int n = 0; n < 4; n++)
            #pragma unroll
            for (int i = 0; i < 4; i++)
                TU[(ewr + 16 * m + i) * 128 + ewc + 16 * n] =
                    f2bf(fmaxf(acc[m][n][i], 0.f));
    __syncthreads();
    #pragma unroll
    for (int q = 0; q < 8; ++q) {
        int chunk = tid + q * 256;       // 128 rows x 16 chunks (16B=8 u16)
        int r = chunk >> 4, c = chunk & 15;
        int row = row0 + r;
        if (row < MC)
            *(bf16x8*)&xs[((long)head * MC + row) * 512 + nn0 + c * 8] =
                *(bf16x8*)&TU[r * 128 + c * 8];
    }
    // ---- pass 2: qr = rope(TU) -- reads TU only, vectorized tables ----
    #pragma unroll
    for (int q = 0; q < 8; ++q) {
        int chunk = tid + q * 256;
        int r = chunk >> 4, c = chunk & 15;
        int row = row0 + r;
        if (row < MC) {
            int t = row % 196;
            int nn = nn0 + c * 8;
            bf16x8 v8 = *(bf16x8*)&TU[r * 128 + c * 8];
            f32x4 cs0 = *(const f32x4*)&tc[t * 512 + nn];
            f32x4 cs1 = *(const f32x4*)&tc[t * 512 + nn + 4];
            f32x4 sn0 = *(const f32x4*)&tsn[t * 512 + nn];
            f32x4 sn1 = *(const f32x4*)&tsn[t * 512 + nn + 4];
            float v[8], qv[8];
            #pragma unroll
            for (int j = 0; j < 8; j++) v[j] = bf2f((u16)v8[j]);
            #pragma unroll
            for (int j = 0; j < 2; j++) {
                qv[2 * j]     = v[2 * j] * cs0[2 * j]     - v[2 * j + 1] * sn0[2 * j];
                qv[2 * j + 1] = v[2 * j + 1] * cs0[2 * j + 1] + v[2 * j] * sn0[2 * j + 1];
                qv[4 + 2 * j]     = v[4 + 2 * j] * cs1[2 * j]     - v[4 + 2 * j + 1] * sn1[2 * j];
                qv[4 + 2 * j + 1] = v[4 + 2 * j + 1] * cs1[2 * j + 1] + v[4 + 2 * j] * sn1[2 * j + 1];
            }
            bf16x8 o8;
            #pragma unroll
            for (int j = 0; j < 8; j++) o8[j] = (short)f2bf(qv[j]);
            *(bf16x8*)&qr[((long)head * MC + row) * 512 + nn] = o8;
        }
    }
}

// ---------------------------------------------------------------------------
// Fused attention + ykv row stats (mu, rs) for the ys LN-fold.
// R16: barrier-free MFMA phases. Scores & PV read fragments DIRECTLY from
// global (L2-resident via R15's XCD/bL remap): one wave-load = 16 rows x
// 64B full lines (lanes=rows, lane-groups=k-slots). No lds_a/lds_b at all.
// LDS: Pl [128][232] + part. 5 barriers total per block.
// ---------------------------------------------------------------------------
__global__ __launch_bounds__(256) void k_attn(const u16* __restrict__ qr,
                                              const u16* __restrict__ hnT,
                                              u16* __restrict__ ykv,
                                              float* __restrict__ stats) {
    __shared__ alignas(16) u16 Pl[128 * 232];
    __shared__ float part[2][128][2];    // [max|sum][row][wave-col-half]
    const int tid = threadIdx.x, lane = tid & 63, wave = tid >> 6;
    const int wr = (wave >> 1) * 64, wc = (wave & 1) * 64;
    const int lr = lane & 15, lk = (lane >> 4) * 8;
    // XCD/bL-locality remap (bijective over 384)
    const int p = blockIdx.x;            // 0..383
    const int xcd = p & 7, slot = p >> 3;          // 8 x 48
    const int bL = 2 * xcd + (slot >= 24);
    const int sub = (slot >= 24) ? slot - 24 : slot;   // 0..23
    const int h = sub >> 1, rt = sub & 1;
    const int bh = h * 16 + bL;
    const int row0 = rt * 128;
    const u16* qbase = qr + (long)bh * 196 * 512;

    f32x4 acc0[4][4], acc1[4][4];
    #pragma unroll
    for (int m = 0; m < 4; m++)
        #pragma unroll
        for (int n = 0; n < 4; n++) {
            acc0[m][n] = (f32x4){0.f, 0.f, 0.f, 0.f};
            acc1[m][n] = (f32x4){0.f, 0.f, 0.f, 0.f};
        }

    // ---- scores: S[r,c] = Q[row0+r].Q[c], cols 0..255, K=512 ----
    // direct global fragment loads; merged col-tiles (A loaded once); no LDS
    {
        const u16* A  = qbase + (long)(row0 + wr + lr) * 512 + lk;
        const u16* B0 = qbase + (long)(wc + lr) * 512 + lk;
        const u16* B1 = qbase + (long)(128 + wc + lr) * 512 + lk;
        for (int k0 = 0; k0 < 16; ++k0) {
            bf16x8 af[4], b0[4], b1[4];
            #pragma unroll
            for (int m = 0; m < 4; m++)
                af[m] = *(const bf16x8*)(A + (long)(16 * m) * 512 + k0 * 32);
            #pragma unroll
            for (int n = 0; n < 4; n++) {
                b0[n] = *(const bf16x8*)(B0 + (long)(16 * n) * 512 + k0 * 32);
                b1[n] = *(const bf16x8*)(B1 + (long)(16 * n) * 512 + k0 * 32);
            }
            #pragma unroll
            for (int m = 0; m < 4; m++)
                #pragma unroll
                for (int n = 0; n < 4; n++) {
                    acc0[m][n] = __builtin_amdgcn_mfma_f32_16x16x32_bf16(
                        af[m], b0[n], acc0[m][n], 0, 0, 0);
                    acc1[m][n] = __builtin_amdgcn_mfma_f32_16x16x32_bf16(
                        af[m], b1[n], acc1[m][n], 0, 0, 0);
                }
        }
    }

    // ---- softmax over cols (valid < 196), scale applied inside exp ----
    const int rb = wr + (lane >> 4) * 4;
    #pragma unroll
    for (int m = 0; m < 4; m++)
        #pragma unroll
        for (int i = 0; i < 4; i++) {
            float mx = -1e30f;
            #pragma unroll
            for (int n = 0; n < 4; n++) {
                int c0 = wc + 16 * n + lr;
                if (c0 < 196) mx = fmaxf(mx, acc0[m][n][i]);
                if (c0 + 128 < 196) mx = fmaxf(mx, acc1[m][n][i]);
            }
            #pragma unroll
            for (int o = 1; o < 16; o <<= 1) mx = fmaxf(mx, __shfl_xor(mx, o));
            if (lr == 0) part[0][rb + 16 * m + i][wave & 1] = mx;
        }
    __syncthreads();
    #pragma unroll
    for (int m = 0; m < 4; m++)
        #pragma unroll
        for (int i = 0; i < 4; i++) {
            int row = rb + 16 * m + i;
            float rmx = fmaxf(part[0][row][0], part[0][row][1]);
            float s = 0.f;
            #pragma unroll
            for (int n = 0; n < 4; n++) {
                int c0 = wc + 16 * n + lr;
                float e0 = (c0 < 196) ? __expf((acc0[m][n][i] - rmx) * SM_SCALE) : 0.f;
                float e1 = (c0 + 128 < 196) ? __expf((acc1[m][n][i] - rmx) * SM_SCALE) : 0.f;
                acc0[m][n][i] = e0; acc1[m][n][i] = e1;
                s += e0 + e1;
            }
            #pragma unroll
            for (int o = 1; o < 16; o <<= 1) s += __shfl_xor(s, o);
            if (lr == 0) part[1][row][wave & 1] = s;
        }
    __syncthreads();
    #pragma unroll
    for (int m = 0; m < 4; m++)
        #pragma unroll
        for (int i = 0; i < 4; i++) {
            int row = rb + 16 * m + i;
            float inv = 1.f / (part[1][row][0] + part[1][row][1]);
            #pragma unroll
            for (int n = 0; n < 4; n++) {
                int c0 = wc + 16 * n + lr;
                Pl[row * 232 + c0] = f2bf(acc0[m][n][i] * inv);
                if (c0 + 128 < 224)
                    Pl[row * 232 + c0 + 128] = f2bf(acc1[m][n][i] * inv);
            }
        }
    __syncthreads();                      // Pl visible
    // part[] now free: zero it for ykv row-stats accumulation
    { float* pf = &part[0][0][0]; pf[tid] = 0.f; pf[tid + 256] = 0.f; }
    __syncthreads();                      // zeroed part visible to owners

    // ---- PV: O[r,d] = sum_s P[r,s]*hnT[d][s]; 6 cd slabs, K=224 ----
    // A from Pl (LDS), B direct from hnT (L2). NO barriers in this loop.
    const u16* hbase = hnT + (long)bL * 768 * 224;
    for (int cd = 0; cd < 6; ++cd) {
        const u16* Bt = hbase + (long)(cd * 128 + wc + lr) * 224 + lk;
        f32x4 pacc[4][4];
        #pragma unroll
        for (int m = 0; m < 4; m++)
            #pragma unroll
            for (int n = 0; n < 4; n++) pacc[m][n] = (f32x4){0.f, 0.f, 0.f, 0.f};
        #pragma unroll
        for (int k0 = 0; k0 < 7; ++k0) {
            bf16x8 af[4], bfr[4];
            #pragma unroll
            for (int m = 0; m < 4; m++)
                af[m] = *(const bf16x8*)&Pl[(wr + 16 * m + lr) * 232 + k0 * 32 + lk];
            #pragma unroll
            for (int n = 0; n < 4; n++)
                bfr[n] = *(const bf16x8*)(Bt + (long)(16 * n) * 224 + k0 * 32);
            #pragma unroll
            for (int m = 0; m < 4; m++)
                #pragma unroll
                for (int n = 0; n < 4; n++)
                    pacc[m][n] = __builtin_amdgcn_mfma_f32_16x16x32_bf16(
                        af[m], bfr[n], pacc[m][n], 0, 0, 0);
        }
        // row-stats partials (each (row, wave-half) slot owned by one thread)
        #pragma unroll
        for (int m = 0; m < 4; m++)
            #pragma unroll
            for (int i = 0; i < 4; i++) {
                float s = pacc[m][0][i] + pacc[m][1][i] + pacc[m][2][i] + pacc[m][3][i];
                float q2 = pacc[m][0][i] * pacc[m][0][i] + pacc[m][1][i] * pacc[m][1][i] +
                           pacc[m][2][i] * pacc[m][2][i] + pacc[m][3][i] * pacc[m][3][i];
                #pragma unroll
                for (int o = 1; o < 16; o <<= 1) {
                    s += __shfl_xor(s, o);
                    q2 += __shfl_xor(q2, o);
                }
                if (lr == 0) {
                    part[0][rb + 16 * m + i][wave & 1] += s;
                    part[1][rb + 16 * m + i][wave & 1] += q2;
                }
            }
        // epilogue: store this d-slab
        {
            const int ewr = wr + (lane >> 4) * 4;
            const int ewc = wc + lr;
            #pragma unroll
            for (int m = 0; m < 4; m++)
                #pragma unroll
                for (int n = 0; n < 4; n++)
                    #pragma unroll
                    for (int i = 0; i < 4; i++) {
                        int trow = row0 + ewr + 16 * m + i;
                        if (trow < 196)
                            ykv[((long)bh * 196 + trow) * 768 + cd * 128 + ewc + 16 * n] =
                                f2bf(pacc[m][n][i]);
                    }
        }
    }
    // finalize row stats
    __syncthreads();
    if (tid < 128) {
        int trow = row0 + tid;
        if (trow < 196) {
            float s = part[0][tid][0] + part[0][tid][1];
            float q2 = part[1][tid][0] + part[1][tid][1];
            float mu = s * (1.f / 768.f);
            float var = q2 * (1.f / 768.f) - mu * mu;
            float2 st;
            st.x = mu;
            st.y = rsqrtf(var + LN_EPS);
            *(float2*)&stats[((long)bh * 196 + trow) * 2] = st;
        }
    }
}

// y_sparse = relu(LN(ykv) @ encv) via fold: rs*(acc - mu*colsum);
// z = x_sparse*y_sparse, head-major flatten. grid (25,4,12), swizzled.
__global__ __launch_bounds__(256) void k_gemm_ys(const u16* __restrict__ ykv,
                                                 const u16* __restrict__ encvt,
                                                 const u16* __restrict__ xs,
                                                 const float* __restrict__ stats,
                                                 const float* __restrict__ colsum,
                                                 u16* __restrict__ z) {
    GEMM64_PROLOGUE
    // XCD swizzle: 1200 wgs, q=150
    int p = blockIdx.x + 25 * (blockIdx.y + 4 * blockIdx.z);
    int w = (p & 7) * 150 + (p >> 3);
    int rt = w % 25, rem = w / 25;
    int ct = rem & 3, h = rem >> 2;
    int row0 = rt * 128, col0 = ct * 128;
    gemm_core64(ykv + ((long)h * MC + row0) * 768, 768,
                encvt + ((long)h * 512 + col0) * 768, 768, 12, acc, lds_a, lds_b);
    EPI_VARS
    const int tid = threadIdx.x;
    u16* TU = lds_ab;                    // [128][128]
    // phase A: vector-load xs tile
    __syncthreads();
    #pragma unroll
    for (int q = 0; q < 8; ++q) {
        int chunk = tid + q * 256;
        int r = chunk >> 4, c = chunk & 15;
        *(bf16x8*)&TU[r * 128 + c * 8] =
            *(const bf16x8*)&xs[((long)h * MC + row0 + r) * 512 + col0 + c * 8];
    }
    __syncthreads();
    // phase B: in-place fold+relu+mul (thread-owned slots)
    #pragma unroll
    for (int m = 0; m < 4; m++)
        #pragma unroll
        for (int i = 0; i < 4; i++) {
            int rloc = ewr + 16 * m + i;
            int row = row0 + rloc;
            float mu = 0.f, rs = 0.f;
            if (row < MC) {
                float2 st = *(const float2*)&stats[((long)h * MC + row) * 2];
                mu = st.x; rs = st.y;
            }
            #pragma unroll
            for (int n = 0; n < 4; n++) {
                int cloc = ewc + 16 * n;
                float cs = colsum[h * 512 + col0 + cloc];
                float v = (acc[m][n][i] - mu * cs) * rs;
                v = fmaxf(v, 0.f) * bf2f(TU[rloc * 128 + cloc]);
                TU[rloc * 128 + cloc] = f2bf(v);
            }
        }
    __syncthreads();
    // phase C: vector-store z tile
    #pragma unroll
    for (int q = 0; q < 8; ++q) {
        int chunk = tid + q * 256;
        int r = chunk >> 4, c = chunk & 15;
        int row = row0 + r;
        if (row < MC)
            *(bf16x8*)&z[(long)row * 6144 + h * 512 + col0 + c * 8] =
                *(bf16x8*)&TU[r * 128 + c * 8];
    }
}

// yMLP_raw partial s = z[:, s*1536:(s+1)*1536] @ dec[s...]  (split-K4)
__global__ __launch_bounds__(256) void k_gemm_mlp(const u16* __restrict__ z,
                                                  const u16* __restrict__ dect,
                                                  float* __restrict__ rawK) {
    GEMM64_PROLOGUE
    // XCD swizzle: grid (25,6,4) -> 600 wgs, q=75
    int p = blockIdx.x + 25 * (blockIdx.y + 6 * blockIdx.z);
    int w = (p & 7) * 75 + (p >> 3);
    int row0 = (w % 25) * 128, col0 = ((w / 25) % 6) * 128, s = w / 150;
    gemm_core64(z + (long)row0 * 6144 + s * 1536, 6144,
                dect + (long)col0 * 6144 + s * 1536, 6144, 24, acc, lds_a, lds_b);
    EPI_VARS
    const int tid = threadIdx.x;
    float* TF = (float*)lds_ab;          // [64][128] f32, two half-passes
    float* raw = rawK + (long)s * MC * 768;
    #pragma unroll
    for (int hf = 0; hf < 2; ++hf) {
        __syncthreads();
        if ((ewr >> 6) == hf) {
            #pragma unroll
            for (int m = 0; m < 4; m++)
                #pragma unroll
                for (int n = 0; n < 4; n++)
                    #pragma unroll
                    for (int i = 0; i < 4; i++)
                        TF[(ewr - hf * 64 + 16 * m + i) * 128 + ewc + 16 * n] =
                            acc[m][n][i];
        }
        __syncthreads();
        #pragma unroll
        for (int q = 0; q < 8; ++q) {
            int chunk = tid + q * 256;
            int r = chunk >> 5, c = chunk & 31;
            int row = row0 + hf * 64 + r;
            if (row < MC)
                *(f32x4*)&raw[(long)row * 768 + col0 + c * 4] =
                    *(f32x4*)&TF[r * 128 + c * 4];
        }
    }
}

// ---------------------------------------------------------------------------
// per-row LN kernels
// ---------------------------------------------------------------------------
// hn = LN(h) -> hn bf16 (used ONCE after tokens; later layers skip: LN(LN)~id)
__global__ __launch_bounds__(256) void k_ln1(const float* __restrict__ h,
                                             u16* __restrict__ hnb) {
    __shared__ float sm[4];
    int r = blockIdx.x, tid = threadIdx.x;
    const float* p = h + (long)r * 768;
    float x0 = p[tid], x1 = p[tid + 256], x2 = p[tid + 512];
    float mean = block_reduce_sum(x0 + x1 + x2, sm) * (1.f / 768.f);
    float d0 = x0 - mean, d1 = x1 - mean, d2 = x2 - mean;
    float var = block_reduce_sum(d0 * d0 + d1 * d1 + d2 * d2, sm) * (1.f / 768.f);
    float rs = rsqrtf(var + LN_EPS);
    long ro = (long)r * 768;
    hnb[ro + tid] = f2bf(d0 * rs);
    hnb[ro + tid + 256] = f2bf(d1 * rs);
    hnb[ro + tid + 512] = f2bf(d2 * rs);
}

// hnT[b][d][tpad224] = hnb[b*196+t][d], t-pad zero-filled. 32x32 LDS tiles.
__global__ __launch_bounds__(256) void k_hnT(const u16* __restrict__ hnb,
                                             u16* __restrict__ hnT) {
    __shared__ u16 tile[32][33];
    int t0 = blockIdx.x * 32, d0 = blockIdx.y * 32, b = blockIdx.z;
    int i = threadIdx.x >> 5, j = threadIdx.x & 31;
    #pragma unroll
    for (int p = 0; p < 4; p++) {
        int t = t0 + i + p * 8;
        tile[i + p * 8][j] = (t < 196) ? hnb[((long)b * 196 + t) * 768 + d0 + j] : (u16)0;
    }
    __syncthreads();
    #pragma unroll
    for (int p = 0; p < 4; p++) {
        int dd = i + p * 8;
        hnT[((long)b * 768 + d0 + dd) * 224 + t0 + j] = tile[j][dd];
    }
}

// hnb = LN(hnb + LN(sum of 4 split-K partials))  [in-place: reads first]
__global__ __launch_bounds__(256) void k_final_h(const float* __restrict__ rawK,
                                                 u16* __restrict__ hnb) {
    __shared__ float sm[4];
    const long PS = (long)MC * 768;
    int r = blockIdx.x, tid = threadIdx.x;
    const float* rp = rawK + (long)r * 768;
    u16* hp = hnb + (long)r * 768;
    float y0 = rp[tid] + rp[tid + PS] + rp[tid + 2 * PS] + rp[tid + 3 * PS];
    float y1 = rp[tid + 256] + rp[tid + 256 + PS] + rp[tid + 256 + 2 * PS] + rp[tid + 256 + 3 * PS];
    float y2 = rp[tid + 512] + rp[tid + 512 + PS] + rp[tid + 512 + 2 * PS] + rp[tid + 512 + 3 * PS];
    float h0 = bf2f(hp[tid]), h1 = bf2f(hp[tid + 256]), h2 = bf2f(hp[tid + 512]);
    float mean = block_reduce_sum(y0 + y1 + y2, sm) * (1.f / 768.f);
    float d0 = y0 - mean, d1 = y1 - mean, d2 = y2 - mean;
    float var = block_reduce_sum(d0 * d0 + d1 * d1 + d2 * d2, sm) * (1.f / 768.f);
    float rs = rsqrtf(var + LN_EPS);
    float s0 = h0 + d0 * rs;
    float s1 = h1 + d1 * rs;
    float s2 = h2 + d2 * rs;
    mean = block_reduce_sum(s0 + s1 + s2, sm) * (1.f / 768.f);
    d0 = s0 - mean; d1 = s1 - mean; d2 = s2 - mean;
    var = block_reduce_sum(d0 * d0 + d1 * d1 + d2 * d2, sm) * (1.f / 768.f);
    rs = rsqrtf(var + LN_EPS);
    hp[tid] = f2bf(d0 * rs);
    hp[tid + 256] = f2bf(d1 * rs);
    hp[tid + 512] = f2bf(d2 * rs);
}

// pool stage 1: partial sums over 14-row groups -> part[b][g][768] (bf16 in)
__global__ __launch_bounds__(256) void k_pool1(const u16* __restrict__ hnb,
                                               float* __restrict__ part) {
    int g = blockIdx.x, b = blockIdx.y, tid = threadIdx.x;
    const u16* base = hnb + ((long)b * 196 + g * 14) * 768;
    float a0 = 0.f, a1 = 0.f, a2 = 0.f;
    for (int t = 0; t < 14; t++) {
        const u16* p = base + (long)t * 768;
        a0 += bf2f(p[tid]); a1 += bf2f(p[tid + 256]); a2 += bf2f(p[tid + 512]);
    }
    float* pp = part + ((long)b * 14 + g) * 768;
    pp[tid] = a0; pp[tid + 256] = a1; pp[tid + 512] = a2;
}

// pool stage 2: pooled = LN(sum(part)/196)
__global__ __launch_bounds__(256) void k_pool2(const float* __restrict__ part,
                                               float* __restrict__ pooled) {
    __shared__ float sm[4];
    int b = blockIdx.x, tid = threadIdx.x;
    const float* pp = part + (long)b * 14 * 768;
    float a0 = 0.f, a1 = 0.f, a2 = 0.f;
    for (int g = 0; g < 14; g++) {
        a0 += pp[g * 768 + tid]; a1 += pp[g * 768 + tid + 256]; a2 += pp[g * 768 + tid + 512];
    }
    a0 *= (1.f / 196.f); a1 *= (1.f / 196.f); a2 *= (1.f / 196.f);
    float mean = block_reduce_sum(a0 + a1 + a2, sm) * (1.f / 768.f);
    float d0 = a0 - mean, d1 = a1 - mean, d2 = a2 - mean;
    float var = block_reduce_sum(d0 * d0 + d1 * d1 + d2 * d2, sm) * (1.f / 768.f);
    float rs = rsqrtf(var + LN_EPS);
    pooled[(long)b * 768 + tid] = d0 * rs;
    pooled[(long)b * 768 + tid + 256] = d1 * rs;
    pooled[(long)b * 768 + tid + 512] = d2 * rs;
}

// out = pooled @ head_w^T + head_b.  grid (250, 64): wave w -> col 4*bx+w.
__global__ __launch_bounds__(256) void k_head(const float* __restrict__ pooled,
                                              const float* __restrict__ hw,
                                              const float* __restrict__ hb,
                                              float* __restrict__ out) {
    __shared__ float pr[768];
    int b = blockIdx.y, tid = threadIdx.x;
    pr[tid] = pooled[(long)b * 768 + tid];
    pr[tid + 256] = pooled[(long)b * 768 + tid + 256];
    pr[tid + 512] = pooled[(long)b * 768 + tid + 512];
    __syncthreads();
    int c = blockIdx.x * 4 + (tid >> 6);
    int lane = tid & 63;
    const float* wrow = hw + (long)c * 768;
    float acc = 0.f;
    #pragma unroll
    for (int k = 0; k < 768; k += 64) acc += pr[k + lane] * wrow[k + lane];
    #pragma unroll
    for (int o = 32; o; o >>= 1) acc += __shfl_xor(acc, o);
    if (lane == 0) out[(long)b * 1000 + c] = acc + hb[c];
}

// ---------------------------------------------------------------------------
extern "C" void kernel_launch(void* const* d_in, const int* in_sizes, int n_in,
                              void* d_out, int out_size, void* d_ws, size_t ws_size,
                              hipStream_t stream) {
    const float* x     = (const float*)d_in[0];
    const float* convw = (const float*)d_in[1];
    const float* convb = (const float*)d_in[2];
    const float* pe    = (const float*)d_in[3];
    const float* enc   = (const float*)d_in[4];
    const float* encv  = (const float*)d_in[5];
    const float* dec   = (const float*)d_in[6];
    const float* freqs = (const float*)d_in[7];
    const float* hw    = (const float*)d_in[8];
    const float* hbias = (const float*)d_in[9];
    float* out = (float*)d_out;

    char* W = (char*)d_ws;
    size_t off = 0;
    auto ALLOC = [&](size_t bytes) {
        size_t o = off;
        off += (bytes + 255) & ~(size_t)255;
        return o;
    };
    // persistent
    float* bh    = (float*)(W + ALLOC(38535168));            // h f32 (setup only)
    u16*   bhnb  = (u16*)  (W + ALLOC(19267584 + 524288));   // hn bf16 (+edge slack)
    u16*   bhnT  = (u16*)  (W + ALLOC(22020096));            // hn^T bf16 (64,768,224)
    u16*   benc  = (u16*)  (W + ALLOC(9437184));             // enc^T  (12,512,768)
    u16*   bencv = (u16*)  (W + ALLOC(9437184));             // encv^T
    u16*   bdec  = (u16*)  (W + ALLOC(9437184));             // dec^T  (768,6144)
    float* btc   = (float*)(W + ALLOC(401408));              // cos (196,512)
    float* bts   = (float*)(W + ALLOC(401408));              // sin
    float* bpool = (float*)(W + ALLOC(196608));              // pooled (64,768)
    float* bpart = (float*)(W + ALLOC(2752512));             // pool partials (64,14,768)
    float* bstats= (float*)(W + ALLOC(301056));              // ykv row stats (192*196 x f32x2)
    float* bcs   = (float*)(W + ALLOC(24576));               // encv colsums (12,512)
    // chunk regions (+slack for masked edge-tile overreads)
    char*  R1    = (char*) (W + ALLOC(38535168 + 2097152));  // qr / z
    char*  R2    = (char*) (W + ALLOC(57802752 + 524288));   // ykv / rawK (+setup patches)
    char*  R3    = (char*) (W + ALLOC(38535168 + 524288));   // xs (+setup conv_w)
    (void)ws_size; (void)in_sizes; (void)n_in; (void)out_size;

    u16*   bap  = (u16*)R2;    // setup: packed patches (18.4M)
    u16*   bcw  = (u16*)R3;    // setup: conv_w bf16 (1.2M)
    u16*   qr   = (u16*)R1;    // per-chunk head-major (192hb,196,512)
    u16*   z    = (u16*)R1;    // (3136,6144)
    u16*   ykv  = (u16*)R2;    // head-major (192hb,196,768)
    float* rawK = (float*)R2;  // yMLP split-K partials 4x(3136,768) f32
    u16*   xs   = (u16*)R3;    // head-major (192hb,196,512)

    // ---- setup ----
    k_pack_patches<<<37632, 256, 0, stream>>>(x, bap);
    k_cast<<<2304, 256, 0, stream>>>(convw, bcw, 768 * 768);
    k_gemm_tokens<<<dim3(98, 6), 256, 0, stream>>>(bap, bcw, convb, pe, bh);
    k_transpose_cast<<<dim3(16, 24, 12), 256, 0, stream>>>(enc, benc, 768, 512);
    k_transpose_cast<<<dim3(16, 24, 12), 256, 0, stream>>>(encv, bencv, 768, 512);
    k_transpose_cast<<<dim3(24, 192, 1), 256, 0, stream>>>(dec, bdec, 6144, 768);
    k_rope_tab<<<392, 256, 0, stream>>>(freqs, btc, bts);
    k_colsum<<<dim3(2, 12), 256, 0, stream>>>(encv, bcs);
    k_ln1<<<12544, 256, 0, stream>>>(bh, bhnb);   // once; thereafter LN(LN)~id

    // ---- 6 shared-weight layers, 4 chunks of 16 images each ----
    for (int L = 0; L < 6; ++L) {
        k_hnT<<<dim3(7, 24, 64), 256, 0, stream>>>(bhnb, bhnT);
        for (int c = 0; c < 4; ++c) {
            long r0 = (long)c * MC;                    // chunk row offset
            k_gemm_xs<<<dim3(25, 48), 256, 0, stream>>>(
                bhnb + r0 * 768, benc, btc, bts, xs, qr);
            k_attn<<<384, 256, 0, stream>>>(
                qr, bhnT + (long)c * 16 * 768 * 224, ykv, bstats);
            k_gemm_ys<<<dim3(25, 4, 12), 256, 0, stream>>>(ykv, bencv, xs, bstats, bcs, z);
            k_gemm_mlp<<<dim3(25, 6, 4), 256, 0, stream>>>(z, bdec, rawK);
            k_final_h<<<MC, 256, 0, stream>>>(rawK, bhnb + r0 * 768);
        }
    }

    // ---- head ----
    k_pool1<<<dim3(14, 64), 256, 0, stream>>>(bhnb, bpart);
    k_pool2<<<64, 256, 0, stream>>>(bpart, bpool);
    k_head<<<dim3(250, 64), 256, 0, stream>>>(bpool, hw, hbias, out);
}

// Round 10
// 6401.524 us; speedup vs baseline: 1.2236x; 1.2236x over previous
//
#include <hip/hip_runtime.h>
#include <hip/hip_bf16.h>

// ============================================================================
// VisionBDHv2 forward, MI355X (gfx950). Round 17.
// R15: 6049us BEST (attn XCD/bL remap + vectorized rope).
// R16: 7833us REGRESSION - direct per-lane global fragment loads can't
//   pipeline (reg pressure) and 4.8MB/XCD working set partially misses L2;
//   LDS-DMA staging is the right data path. Reverted.
// R17 = R15 + attn TLP: 64-row tiles, grid 768 (3 blocks/CU, was 1.5):
//   - 4 waves x 64-col slices of the 256 score cols (single acc[4][4]);
//     LDS 51KB (Sa4K+Sb16K+Pl29.7K+part2K) -> 3 blocks/CU, 12 waves/CU.
//   - thin serial drain-steps kept (R13 lesson): scores 16 steps (1A+4B
//     gload16), PV 3 passes x 7 steps x 4 gload16; 37 steps/block vs 74,
//     2x blocks -> same aggregate work, 2x interleave partners per stall.
//   - softmax row-reduce via part[.][row][4] (col-slice per wave).
//   - remap: xcd=p&7, per-XCD 2bL x 12h x 4rt (bijective, L2-local).
// Everything else identical to R15.
// ============================================================================

typedef short bf16x8 __attribute__((ext_vector_type(8)));
typedef float f32x4 __attribute__((ext_vector_type(4)));
typedef unsigned short u16;

#define LN_EPS 1e-5f
#define SM_SCALE 0.044194173824159216f  /* 1/sqrt(512) */
#define TWO_PI 6.283185307179586f
#define MC 3136                          /* rows per chunk = 16*196 */

typedef __attribute__((address_space(3))) unsigned char* as3p;
typedef const __attribute__((address_space(1))) unsigned char* as1p;

__device__ __forceinline__ void gload16(const u16* g, u16* l) {
    __builtin_amdgcn_global_load_lds((as1p)(const void*)g, (as3p)(void*)l, 16, 0, 0);
}

__device__ __forceinline__ u16 f2bf(float f) {
    __hip_bfloat16 h = __float2bfloat16(f);
    return *reinterpret_cast<u16*>(&h);
}
__device__ __forceinline__ float bf2f(u16 u) {
    return __uint_as_float(((unsigned)u) << 16);
}

// ---------------------------------------------------------------------------
// block reductions (256 threads, 4 waves)
// ---------------------------------------------------------------------------
__device__ __forceinline__ float block_reduce_sum(float v, float* sm) {
    #pragma unroll
    for (int o = 32; o; o >>= 1) v += __shfl_xor(v, o);
    if ((threadIdx.x & 63) == 0) sm[threadIdx.x >> 6] = v;
    __syncthreads();
    float r = sm[0] + sm[1] + sm[2] + sm[3];
    __syncthreads();
    return r;
}

// ---------------------------------------------------------------------------
// GEMM core (R7/R11 gemm_core64, verbatim): BK=64, swizzled, 128x128 tile,
// 4 waves (2x2). LDS [128][64] u16 per operand; physical slot s holds
// logical col-slot s^(row&7). Staged via global_load_lds with pre-swizzled
// global source (linear LDS dest). ds_read applies same XOR. C/D: elem i ->
// row (lane>>4)*4+i, col lane&15.
// ---------------------------------------------------------------------------
__device__ __forceinline__ void gemm_core64(const u16* __restrict__ A, int lda,
                                            const u16* __restrict__ Bt, int ldb,
                                            int ksteps, f32x4 acc[4][4],
                                            u16* lds_a, u16* lds_b) {
    const int tid = threadIdx.x;
    const int lane = tid & 63;
    const int wave = tid >> 6;
    const int wr = (wave >> 1) * 64;
    const int wc = (wave & 1) * 64;
    const int lr = lane & 15;
    const int lg = lane >> 4;            // logical k-slot base (0..3)
    const int rx = lr & 7;               // row&7 for this lane's fragment rows
    const int srow = tid >> 3;           // staging row within 32-row group
    const int gslot = (tid & 7) ^ (srow & 7);  // pre-swizzled global col slot
    const u16* ga = A + (long)srow * lda + gslot * 8;
    const u16* gb = Bt + (long)srow * ldb + gslot * 8;
    u16* la = lds_a + tid * 8;           // linear dest: row srow, slot tid&7
    u16* lb = lds_b + tid * 8;
    for (int k0 = 0; k0 < ksteps; ++k0) {
        __syncthreads();                 // prior iteration's reads done
        #pragma unroll
        for (int j = 0; j < 4; ++j) {    // 32-row groups (row&7 invariant)
            gload16(ga + (long)(j * 32) * lda, la + j * 2048);
            gload16(gb + (long)(j * 32) * ldb, lb + j * 2048);
        }
        ga += 64; gb += 64;
        __syncthreads();                 // drains vmcnt(0) before barrier
        bf16x8 af[2][4], bfr[2][4];
        #pragma unroll
        for (int kk = 0; kk < 2; ++kk) {
            const int ps = ((lg + kk * 4) ^ rx) * 8;   // physical elem offset
            #pragma unroll
            for (int m = 0; m < 4; m++)
                af[kk][m] = *(const bf16x8*)&lds_a[(wr + 16 * m + lr) * 64 + ps];
            #pragma unroll
            for (int n = 0; n < 4; n++)
                bfr[kk][n] = *(const bf16x8*)&lds_b[(wc + 16 * n + lr) * 64 + ps];
        }
        #pragma unroll
        for (int kk = 0; kk < 2; ++kk)
            #pragma unroll
            for (int m = 0; m < 4; m++)
                #pragma unroll
                for (int n = 0; n < 4; n++)
                    acc[m][n] = __builtin_amdgcn_mfma_f32_16x16x32_bf16(
                        af[kk][m], bfr[kk][n], acc[m][n], 0, 0, 0);
    }
}

// merged 32KB LDS: gemm uses [lds_a | lds_b]; epilogue reuses as one tile
// (TU u16[128][128] or TF f32[64][128]).
#define GEMM64_PROLOGUE                                 \
    __shared__ alignas(16) u16 lds_ab[2 * 128 * 64];    \
    u16* lds_a = lds_ab;                                \
    u16* lds_b = lds_ab + 128 * 64;                     \
    f32x4 acc[4][4];                                    \
    _Pragma("unroll")                                   \
    for (int m = 0; m < 4; m++)                         \
        _Pragma("unroll")                               \
        for (int n = 0; n < 4; n++)                     \
            acc[m][n] = (f32x4){0.f, 0.f, 0.f, 0.f};

#define EPI_VARS                                        \
    const int lane = threadIdx.x & 63;                  \
    const int wave = threadIdx.x >> 6;                  \
    const int ewr = (wave >> 1) * 64 + (lane >> 4) * 4; \
    const int ewc = (wave & 1) * 64 + (lane & 15);

// ---------------------------------------------------------------------------
// setup kernels
// ---------------------------------------------------------------------------
__global__ __launch_bounds__(256) void k_pack_patches(const float* __restrict__ x,
                                                      u16* __restrict__ ap) {
    int idx = blockIdx.x * 256 + threadIdx.x;           // < 12544*768
    int r = idx / 768, k = idx - r * 768;
    int b = r / 196, t = r - b * 196;
    int hp = t / 14, wp = t - hp * 14;
    int c = k >> 8, rem = k & 255, p = rem >> 4, q = rem & 15;
    long src = ((long)(b * 3 + c) * 224 + hp * 16 + p) * 224 + wp * 16 + q;
    ap[idx] = f2bf(x[src]);
}

__global__ __launch_bounds__(256) void k_cast(const float* __restrict__ s,
                                              u16* __restrict__ d, int n) {
    int i = blockIdx.x * 256 + threadIdx.x;
    if (i < n) d[i] = f2bf(s[i]);
}

// src (batch, R, C) f32 -> dst (batch, C, R) bf16
__global__ __launch_bounds__(256) void k_transpose_cast(const float* __restrict__ src,
                                                        u16* __restrict__ dst,
                                                        int R, int C) {
    __shared__ float tile[32][33];
    int c0 = blockIdx.x * 32, r0 = blockIdx.y * 32;
    long base = (long)blockIdx.z * R * C;
    int i = threadIdx.x >> 5, j = threadIdx.x & 31;
    #pragma unroll
    for (int p = 0; p < 4; p++) {
        int rr = i + p * 8;
        tile[rr][j] = src[base + (long)(r0 + rr) * C + c0 + j];
    }
    __syncthreads();
    #pragma unroll
    for (int p = 0; p < 4; p++) {
        int rr = i + p * 8;
        dst[base + (long)(c0 + rr) * R + r0 + j] = f2bf(tile[j][rr]);
    }
}

__global__ __launch_bounds__(256) void k_rope_tab(const float* __restrict__ freqs,
                                                  float* __restrict__ tc,
                                                  float* __restrict__ ts) {
    int idx = blockIdx.x * 256 + threadIdx.x;           // < 196*512
    int t = idx >> 9, n = idx & 511;
    float ph = (float)t * freqs[n];
    ph = (ph - floorf(ph)) * TWO_PI;
    tc[idx] = cosf(ph);
    ts[idx] = sinf(ph);
}

// colsum[h][c] = sum_d encv[h][d][c]  (from f32 encv, coalesced in c)
__global__ __launch_bounds__(256) void k_colsum(const float* __restrict__ encv,
                                                float* __restrict__ cs) {
    int h = blockIdx.y, c = blockIdx.x * 256 + threadIdx.x;   // grid (2,12)
    const float* base = encv + (long)h * 768 * 512 + c;
    float a = 0.f;
    for (int d = 0; d < 768; d++) a += base[(long)d * 512];
    cs[h * 512 + c] = a;
}

// ---------------------------------------------------------------------------
// GEMM kernels (R11 core + LDS-bounce epilogues)
// ---------------------------------------------------------------------------
// tokens = patches @ convw^T + bias + pos_embed -> h   (M=12544,K=768,N=768)
__global__ __launch_bounds__(256) void k_gemm_tokens(const u16* __restrict__ ap,
                                                     const u16* __restrict__ bw,
                                                     const float* __restrict__ cb,
                                                     const float* __restrict__ pe,
                                                     float* __restrict__ hout) {
    GEMM64_PROLOGUE
    int row0 = blockIdx.x * 128, col0 = blockIdx.y * 128;
    gemm_core64(ap + (long)row0 * 768, 768, bw + (long)col0 * 768, 768, 12, acc, lds_a, lds_b);
    EPI_VARS
    const int tid = threadIdx.x;
    float* TF = (float*)lds_ab;          // [64][128] f32, two half-passes
    #pragma unroll
    for (int hf = 0; hf < 2; ++hf) {
        __syncthreads();
        if ((ewr >> 6) == hf) {
            #pragma unroll
            for (int m = 0; m < 4; m++)
                #pragma unroll
                for (int n = 0; n < 4; n++)
                    #pragma unroll
                    for (int i = 0; i < 4; i++) {
                        int row = row0 + ewr + 16 * m + i;
                        int col = col0 + ewc + 16 * n;
                        int t = row % 196;
                        TF[(ewr - hf * 64 + 16 * m + i) * 128 + ewc + 16 * n] =
                            acc[m][n][i] + cb[col] + pe[t * 768 + col];
                    }
        }
        __syncthreads();
        #pragma unroll
        for (int q = 0; q < 8; ++q) {
            int chunk = tid + q * 256;   // 64 rows x 32 chunks (16B=4 f32)
            int r = chunk >> 5, c = chunk & 31;
            *(f32x4*)&hout[(long)(row0 + hf * 64 + r) * 768 + col0 + c * 4] =
                *(f32x4*)&TF[r * 128 + c * 4];
        }
    }
}

// chunk: x_sparse = relu(hn@enc); qr = rope(x_sparse)  (M=3136 masked, N=6144)
// xs/qr written HEAD-MAJOR: [(head*16+bL)*196 + t][512]
// R15: rope pass vectorized (TU readback + f32x4 tables + in-reg pair rotate)
__global__ __launch_bounds__(256) void k_gemm_xs(const u16* __restrict__ hnb,
                                                 const u16* __restrict__ enct,
                                                 const float* __restrict__ tc,
                                                 const float* __restrict__ tsn,
                                                 u16* __restrict__ xs,
                                                 u16* __restrict__ qr) {
    GEMM64_PROLOGUE
    // XCD swizzle: grid (25,48) -> 1200 wgs, q=150
    int p = blockIdx.x + 25 * blockIdx.y;
    int w = (p & 7) * 150 + (p >> 3);
    int row0 = (w % 25) * 128, col0 = (w / 25) * 128;
    int head = col0 >> 9, nn0 = col0 & 511;
    gemm_core64(hnb + (long)row0 * 768, 768,
                enct + ((long)head * 512 + nn0) * 768, 768, 12, acc, lds_a, lds_b);
    EPI_VARS
    const int tid = threadIdx.x;
    u16* TU = lds_ab;                    // [128][128] u16
    // ---- pass 1: xs = relu(acc) -> TU -> vector store ----
    __syncthreads();
    #pragma unroll
    for (int m = 0; m < 4; m++)
        #pragma unroll
        for (int n = 0; n < 4; n++)
            #pragma unroll
            for (int i = 0; i < 4; i++)
                TU[(ewr + 16 * m + i) * 128 + ewc + 16 * n] =
                    f2bf(fmaxf(acc[m][n][i], 0.f));
    __syncthreads();
    #pragma unroll
    for (int q = 0; q < 8; ++q) {
        int chunk = tid + q * 256;       // 128 rows x 16 chunks (16B=8 u16)
        int r = chunk >> 4, c = chunk & 15;
        int row = row0 + r;
        if (row < MC)
            *(bf16x8*)&xs[((long)head * MC + row) * 512 + nn0 + c * 8] =
                *(bf16x8*)&TU[r * 128 + c * 8];
    }
    // ---- pass 2: qr = rope(TU) -- reads TU only, vectorized tables ----
    #pragma unroll
    for (int q = 0; q < 8; ++q) {
        int chunk = tid + q * 256;
        int r = chunk >> 4, c = chunk & 15;
        int row = row0 + r;
        if (row < MC) {
            int t = row % 196;
            int nn = nn0 + c * 8;
            bf16x8 v8 = *(bf16x8*)&TU[r * 128 + c * 8];
            f32x4 cs0 = *(const f32x4*)&tc[t * 512 + nn];
            f32x4 cs1 = *(const f32x4*)&tc[t * 512 + nn + 4];
            f32x4 sn0 = *(const f32x4*)&tsn[t * 512 + nn];
            f32x4 sn1 = *(const f32x4*)&tsn[t * 512 + nn + 4];
            float v[8], qv[8];
            #pragma unroll
            for (int j = 0; j < 8; j++) v[j] = bf2f((u16)v8[j]);
            #pragma unroll
            for (int j = 0; j < 2; j++) {
                qv[2 * j]     = v[2 * j] * cs0[2 * j]     - v[2 * j + 1] * sn0[2 * j];
                qv[2 * j + 1] = v[2 * j + 1] * cs0[2 * j + 1] + v[2 * j] * sn0[2 * j + 1];
                qv[4 + 2 * j]     = v[4 + 2 * j] * cs1[2 * j]     - v[4 + 2 * j + 1] * sn1[2 * j];
                qv[4 + 2 * j + 1] = v[4 + 2 * j + 1] * cs1[2 * j + 1] + v[4 + 2 * j] * sn1[2 * j + 1];
            }
            bf16x8 o8;
            #pragma unroll
            for (int j = 0; j < 8; j++) o8[j] = (short)f2bf(qv[j]);
            *(bf16x8*)&qr[((long)head * MC + row) * 512 + nn] = o8;
        }
    }
}

// ---------------------------------------------------------------------------
// Fused attention + ykv row stats (mu, rs) for the ys LN-fold.
// R17: 64-row tiles, grid 768 (3 blocks/CU). 4 waves each own a 64-col slice
// of the 256 score cols (single acc[4][4]); thin serial LDS-DMA drain-steps
// (proven path); softmax cross-wave reduce via part[.][row][4].
// Remap: xcd = p&7; per-XCD = 2 bL x 12 h x 4 rt (L2-local, bijective).
// LDS: Sa 4K + Sb 16K + Pl 29.7K + part 2K = 51KB.
// ---------------------------------------------------------------------------
__global__ __launch_bounds__(256) void k_attn(const u16* __restrict__ qr,
                                              const u16* __restrict__ hnT,
                                              u16* __restrict__ ykv,
                                              float* __restrict__ stats) {
    __shared__ alignas(16) u16 Sa[64 * 32];
    __shared__ alignas(16) u16 Sb[256 * 32];
    __shared__ alignas(16) u16 Pl[64 * 232];
    __shared__ float part[2][64][4];     // [max|sum][row][wave]
    const int tid = threadIdx.x, lane = tid & 63, wave = tid >> 6;
    const int wc = wave * 64;            // this wave's col-slice origin
    const int lr = lane & 15, lk = (lane >> 4) * 8;
    // remap (bijective over 768): per XCD 2bL x 12h x 4rt
    const int p = blockIdx.x;
    const int xcd = p & 7, slot = p >> 3;          // 8 x 96
    const int bL = 2 * xcd + (slot >= 48);
    const int sub = (slot >= 48) ? slot - 48 : slot;   // 0..47
    const int h = sub >> 2, rt = sub & 3;
    const int bh = h * 16 + bL;
    const int row0 = rt * 64;
    const u16* qbase = qr + (long)bh * 196 * 512;
    const int srow = tid >> 2, scol = (tid & 3) * 8;
    const int rb = (lane >> 4) * 4;      // row base within fragment

    f32x4 acc[4][4];
    #pragma unroll
    for (int m = 0; m < 4; m++)
        #pragma unroll
        for (int n = 0; n < 4; n++) acc[m][n] = (f32x4){0.f, 0.f, 0.f, 0.f};

    // ---- scores: S[r, c] = Q[row0+r].Q[c], r<64, c<256, K=512, 16 steps ----
    {
        const u16* ga = qbase + (long)(row0 + srow) * 512 + scol;
        const u16* gb = qbase + (long)srow * 512 + scol;
        for (int k0 = 0; k0 < 16; ++k0) {
            __syncthreads();             // prior step's reads done
            gload16(ga + k0 * 32, Sa + tid * 8);
            #pragma unroll
            for (int jj = 0; jj < 4; ++jj)
                gload16(gb + (long)(jj * 64) * 512 + k0 * 32, Sb + jj * 2048 + tid * 8);
            __syncthreads();             // drain vmcnt(0)
            bf16x8 af[4], bfr[4];
            #pragma unroll
            for (int m = 0; m < 4; m++)
                af[m] = *(const bf16x8*)&Sa[(16 * m + lr) * 32 + lk];
            #pragma unroll
            for (int n = 0; n < 4; n++)
                bfr[n] = *(const bf16x8*)&Sb[(wc + 16 * n + lr) * 32 + lk];
            #pragma unroll
            for (int m = 0; m < 4; m++)
                #pragma unroll
                for (int n = 0; n < 4; n++)
                    acc[m][n] = __builtin_amdgcn_mfma_f32_16x16x32_bf16(
                        af[m], bfr[n], acc[m][n], 0, 0, 0);
        }
    }

    // ---- softmax over cols (valid < 196), 4-slot cross-wave reduce ----
    #pragma unroll
    for (int m = 0; m < 4; m++)
        #pragma unroll
        for (int i = 0; i < 4; i++) {
            float mx = -1e30f;
            #pragma unroll
            for (int n = 0; n < 4; n++) {
                int c0 = wc + 16 * n + lr;
                if (c0 < 196) mx = fmaxf(mx, acc[m][n][i]);
            }
            #pragma unroll
            for (int o = 1; o < 16; o <<= 1) mx = fmaxf(mx, __shfl_xor(mx, o));
            if (lr == 0) part[0][rb + 16 * m + i][wave] = mx;
        }
    __syncthreads();
    #pragma unroll
    for (int m = 0; m < 4; m++)
        #pragma unroll
        for (int i = 0; i < 4; i++) {
            int row = rb + 16 * m + i;
            float rmx = fmaxf(fmaxf(part[0][row][0], part[0][row][1]),
                              fmaxf(part[0][row][2], part[0][row][3]));
            float s = 0.f;
            #pragma unroll
            for (int n = 0; n < 4; n++) {
                int c0 = wc + 16 * n + lr;
                float e = (c0 < 196) ? __expf((acc[m][n][i] - rmx) * SM_SCALE) : 0.f;
                acc[m][n][i] = e;
                s += e;
            }
            #pragma unroll
            for (int o = 1; o < 16; o <<= 1) s += __shfl_xor(s, o);
            if (lr == 0) part[1][row][wave] = s;
        }
    __syncthreads();
    #pragma unroll
    for (int m = 0; m < 4; m++)
        #pragma unroll
        for (int i = 0; i < 4; i++) {
            int row = rb + 16 * m + i;
            float inv = 1.f / (part[1][row][0] + part[1][row][1] +
                               part[1][row][2] + part[1][row][3]);
            #pragma unroll
            for (int n = 0; n < 4; n++) {
                int c0 = wc + 16 * n + lr;
                if (c0 < 224)
                    Pl[row * 232 + c0] = f2bf(acc[m][n][i] * inv);
            }
        }
    __syncthreads();                      // Pl visible
    // part[] now free: zero it for ykv row-stats accumulation
    { float* pf = &part[0][0][0]; pf[tid] = 0.f; pf[tid + 256] = 0.f; }
    __syncthreads();

    // ---- PV: O[r,d] = sum_s P[r,s]*hnT[d][s]; 3 passes x 256 d-cols ----
    const u16* hbase = hnT + (long)bL * 768 * 224;
    for (int j = 0; j < 3; ++j) {
        const u16* gb = hbase + (long)(j * 256 + srow) * 224 + scol;
        f32x4 pacc[4][4];
        #pragma unroll
        for (int m = 0; m < 4; m++)
            #pragma unroll
            for (int n = 0; n < 4; n++) pacc[m][n] = (f32x4){0.f, 0.f, 0.f, 0.f};
        for (int k0 = 0; k0 < 7; ++k0) {
            __syncthreads();             // prior step's Sb reads done
            #pragma unroll
            for (int jj = 0; jj < 4; ++jj)
                gload16(gb + (long)(jj * 64) * 224 + k0 * 32, Sb + jj * 2048 + tid * 8);
            __syncthreads();             // drain
            bf16x8 af[4], bfr[4];
            #pragma unroll
            for (int m = 0; m < 4; m++)
                af[m] = *(const bf16x8*)&Pl[(16 * m + lr) * 232 + k0 * 32 + lk];
            #pragma unroll
            for (int n = 0; n < 4; n++)
                bfr[n] = *(const bf16x8*)&Sb[(wc + 16 * n + lr) * 32 + lk];
            #pragma unroll
            for (int m = 0; m < 4; m++)
                #pragma unroll
                for (int n = 0; n < 4; n++)
                    pacc[m][n] = __builtin_amdgcn_mfma_f32_16x16x32_bf16(
                        af[m], bfr[n], pacc[m][n], 0, 0, 0);
        }
        // row-stats partials (slot (row,wave) owned by one lane; += per pass)
        #pragma unroll
        for (int m = 0; m < 4; m++)
            #pragma unroll
            for (int i = 0; i < 4; i++) {
                float s = pacc[m][0][i] + pacc[m][1][i] + pacc[m][2][i] + pacc[m][3][i];
                float q2 = pacc[m][0][i] * pacc[m][0][i] + pacc[m][1][i] * pacc[m][1][i] +
                           pacc[m][2][i] * pacc[m][2][i] + pacc[m][3][i] * pacc[m][3][i];
                #pragma unroll
                for (int o = 1; o < 16; o <<= 1) {
                    s += __shfl_xor(s, o);
                    q2 += __shfl_xor(q2, o);
                }
                if (lr == 0) {
                    part[0][rb + 16 * m + i][wave] += s;
                    part[1][rb + 16 * m + i][wave] += q2;
                }
            }
        // epilogue: store this 256-col d-slab (wave slice)
        #pragma unroll
        for (int m = 0; m < 4; m++)
            #pragma unroll
            for (int n = 0; n < 4; n++)
                #pragma unroll
                for (int i = 0; i < 4; i++) {
                    int trow = row0 + rb + 16 * m + i;
                    if (trow < 196)
                        ykv[((long)bh * 196 + trow) * 768 + j * 256 + wc + 16 * n + lr] =
                            f2bf(pacc[m][n][i]);
                }
    }
    // finalize row stats
    __syncthreads();
    if (tid < 64) {
        int trow = row0 + tid;
        if (trow < 196) {
            float s = part[0][tid][0] + part[0][tid][1] + part[0][tid][2] + part[0][tid][3];
            float q2 = part[1][tid][0] + part[1][tid][1] + part[1][tid][2] + part[1][tid][3];
            float mu = s * (1.f / 768.f);
            float var = q2 * (1.f / 768.f) - mu * mu;
            float2 st;
            st.x = mu;
            st.y = rsqrtf(var + LN_EPS);
            *(float2*)&stats[((long)bh * 196 + trow) * 2] = st;
        }
    }
}

// y_sparse = relu(LN(ykv) @ encv) via fold: rs*(acc - mu*colsum);
// z = x_sparse*y_sparse, head-major flatten. grid (25,4,12), swizzled.
__global__ __launch_bounds__(256) void k_gemm_ys(const u16* __restrict__ ykv,
                                                 const u16* __restrict__ encvt,
                                                 const u16* __restrict__ xs,
                                                 const float* __restrict__ stats,
                                                 const float* __restrict__ colsum,
                                                 u16* __restrict__ z) {
    GEMM64_PROLOGUE
    // XCD swizzle: 1200 wgs, q=150
    int p = blockIdx.x + 25 * (blockIdx.y + 4 * blockIdx.z);
    int w = (p & 7) * 150 + (p >> 3);
    int rt = w % 25, rem = w / 25;
    int ct = rem & 3, h = rem >> 2;
    int row0 = rt * 128, col0 = ct * 128;
    gemm_core64(ykv + ((long)h * MC + row0) * 768, 768,
                encvt + ((long)h * 512 + col0) * 768, 768, 12, acc, lds_a, lds_b);
    EPI_VARS
    const int tid = threadIdx.x;
    u16* TU = lds_ab;                    // [128][128]
    // phase A: vector-load xs tile
    __syncthreads();
    #pragma unroll
    for (int q = 0; q < 8; ++q) {
        int chunk = tid + q * 256;
        int r = chunk >> 4, c = chunk & 15;
        *(bf16x8*)&TU[r * 128 + c * 8] =
            *(const bf16x8*)&xs[((long)h * MC + row0 + r) * 512 + col0 + c * 8];
    }
    __syncthreads();
    // phase B: in-place fold+relu+mul (thread-owned slots)
    #pragma unroll
    for (int m = 0; m < 4; m++)
        #pragma unroll
        for (int i = 0; i < 4; i++) {
            int rloc = ewr + 16 * m + i;
            int row = row0 + rloc;
            float mu = 0.f, rs = 0.f;
            if (row < MC) {
                float2 st = *(const float2*)&stats[((long)h * MC + row) * 2];
                mu = st.x; rs = st.y;
            }
            #pragma unroll
            for (int n = 0; n < 4; n++) {
                int cloc = ewc + 16 * n;
                float cs = colsum[h * 512 + col0 + cloc];
                float v = (acc[m][n][i] - mu * cs) * rs;
                v = fmaxf(v, 0.f) * bf2f(TU[rloc * 128 + cloc]);
                TU[rloc * 128 + cloc] = f2bf(v);
            }
        }
    __syncthreads();
    // phase C: vector-store z tile
    #pragma unroll
    for (int q = 0; q < 8; ++q) {
        int chunk = tid + q * 256;
        int r = chunk >> 4, c = chunk & 15;
        int row = row0 + r;
        if (row < MC)
            *(bf16x8*)&z[(long)row * 6144 + h * 512 + col0 + c * 8] =
                *(bf16x8*)&TU[r * 128 + c * 8];
    }
}

// yMLP_raw partial s = z[:, s*1536:(s+1)*1536] @ dec[s...]  (split-K4)
__global__ __launch_bounds__(256) void k_gemm_mlp(const u16* __restrict__ z,
                                                  const u16* __restrict__ dect,
                                                  float* __restrict__ rawK) {
    GEMM64_PROLOGUE
    // XCD swizzle: grid (25,6,4) -> 600 wgs, q=75
    int p = blockIdx.x + 25 * (blockIdx.y + 6 * blockIdx.z);
    int w = (p & 7) * 75 + (p >> 3);
    int row0 = (w % 25) * 128, col0 = ((w / 25) % 6) * 128, s = w / 150;
    gemm_core64(z + (long)row0 * 6144 + s * 1536, 6144,
                dect + (long)col0 * 6144 + s * 1536, 6144, 24, acc, lds_a, lds_b);
    EPI_VARS
    const int tid = threadIdx.x;
    float* TF = (float*)lds_ab;          // [64][128] f32, two half-passes
    float* raw = rawK + (long)s * MC * 768;
    #pragma unroll
    for (int hf = 0; hf < 2; ++hf) {
        __syncthreads();
        if ((ewr >> 6) == hf) {
            #pragma unroll
            for (int m = 0; m < 4; m++)
                #pragma unroll
                for (int n = 0; n < 4; n++)
                    #pragma unroll
                    for (int i = 0; i < 4; i++)
                        TF[(ewr - hf * 64 + 16 * m + i) * 128 + ewc + 16 * n] =
                            acc[m][n][i];
        }
        __syncthreads();
        #pragma unroll
        for (int q = 0; q < 8; ++q) {
            int chunk = tid + q * 256;
            int r = chunk >> 5, c = chunk & 31;
            int row = row0 + hf * 64 + r;
            if (row < MC)
                *(f32x4*)&raw[(long)row * 768 + col0 + c * 4] =
                    *(f32x4*)&TF[r * 128 + c * 4];
        }
    }
}

// ---------------------------------------------------------------------------
// per-row LN kernels
// ---------------------------------------------------------------------------
// hn = LN(h) -> hn bf16 (used ONCE after tokens; later layers skip: LN(LN)~id)
__global__ __launch_bounds__(256) void k_ln1(const float* __restrict__ h,
                                             u16* __restrict__ hnb) {
    __shared__ float sm[4];
    int r = blockIdx.x, tid = threadIdx.x;
    const float* p = h + (long)r * 768;
    float x0 = p[tid], x1 = p[tid + 256], x2 = p[tid + 512];
    float mean = block_reduce_sum(x0 + x1 + x2, sm) * (1.f / 768.f);
    float d0 = x0 - mean, d1 = x1 - mean, d2 = x2 - mean;
    float var = block_reduce_sum(d0 * d0 + d1 * d1 + d2 * d2, sm) * (1.f / 768.f);
    float rs = rsqrtf(var + LN_EPS);
    long ro = (long)r * 768;
    hnb[ro + tid] = f2bf(d0 * rs);
    hnb[ro + tid + 256] = f2bf(d1 * rs);
    hnb[ro + tid + 512] = f2bf(d2 * rs);
}

// hnT[b][d][tpad224] = hnb[b*196+t][d], t-pad zero-filled. 32x32 LDS tiles.
__global__ __launch_bounds__(256) void k_hnT(const u16* __restrict__ hnb,
                                             u16* __restrict__ hnT) {
    __shared__ u16 tile[32][33];
    int t0 = blockIdx.x * 32, d0 = blockIdx.y * 32, b = blockIdx.z;
    int i = threadIdx.x >> 5, j = threadIdx.x & 31;
    #pragma unroll
    for (int p = 0; p < 4; p++) {
        int t = t0 + i + p * 8;
        tile[i + p * 8][j] = (t < 196) ? hnb[((long)b * 196 + t) * 768 + d0 + j] : (u16)0;
    }
    __syncthreads();
    #pragma unroll
    for (int p = 0; p < 4; p++) {
        int dd = i + p * 8;
        hnT[((long)b * 768 + d0 + dd) * 224 + t0 + j] = tile[j][dd];
    }
}

// hnb = LN(hnb + LN(sum of 4 split-K partials))  [in-place: reads first]
__global__ __launch_bounds__(256) void k_final_h(const float* __restrict__ rawK,
                                                 u16* __restrict__ hnb) {
    __shared__ float sm[4];
    const long PS = (long)MC * 768;
    int r = blockIdx.x, tid = threadIdx.x;
    const float* rp = rawK + (long)r * 768;
    u16* hp = hnb + (long)r * 768;
    float y0 = rp[tid] + rp[tid + PS] + rp[tid + 2 * PS] + rp[tid + 3 * PS];
    float y1 = rp[tid + 256] + rp[tid + 256 + PS] + rp[tid + 256 + 2 * PS] + rp[tid + 256 + 3 * PS];
    float y2 = rp[tid + 512] + rp[tid + 512 + PS] + rp[tid + 512 + 2 * PS] + rp[tid + 512 + 3 * PS];
    float h0 = bf2f(hp[tid]), h1 = bf2f(hp[tid + 256]), h2 = bf2f(hp[tid + 512]);
    float mean = block_reduce_sum(y0 + y1 + y2, sm) * (1.f / 768.f);
    float d0 = y0 - mean, d1 = y1 - mean, d2 = y2 - mean;
    float var = block_reduce_sum(d0 * d0 + d1 * d1 + d2 * d2, sm) * (1.f / 768.f);
    float rs = rsqrtf(var + LN_EPS);
    float s0 = h0 + d0 * rs;
    float s1 = h1 + d1 * rs;
    float s2 = h2 + d2 * rs;
    mean = block_reduce_sum(s0 + s1 + s2, sm) * (1.f / 768.f);
    d0 = s0 - mean; d1 = s1 - mean; d2 = s2 - mean;
    var = block_reduce_sum(d0 * d0 + d1 * d1 + d2 * d2, sm) * (1.f / 768.f);
    rs = rsqrtf(var + LN_EPS);
    hp[tid] = f2bf(d0 * rs);
    hp[tid + 256] = f2bf(d1 * rs);
    hp[tid + 512] = f2bf(d2 * rs);
}

// pool stage 1: partial sums over 14-row groups -> part[b][g][768] (bf16 in)
__global__ __launch_bounds__(256) void k_pool1(const u16* __restrict__ hnb,
                                               float* __restrict__ part) {
    int g = blockIdx.x, b = blockIdx.y, tid = threadIdx.x;
    const u16* base = hnb + ((long)b * 196 + g * 14) * 768;
    float a0 = 0.f, a1 = 0.f, a2 = 0.f;
    for (int t = 0; t < 14; t++) {
        const u16* p = base + (long)t * 768;
        a0 += bf2f(p[tid]); a1 += bf2f(p[tid + 256]); a2 += bf2f(p[tid + 512]);
    }
    float* pp = part + ((long)b * 14 + g) * 768;
    pp[tid] = a0; pp[tid + 256] = a1; pp[tid + 512] = a2;
}

// pool stage 2: pooled = LN(sum(part)/196)
__global__ __launch_bounds__(256) void k_pool2(const float* __restrict__ part,
                                               float* __restrict__ pooled) {
    __shared__ float sm[4];
    int b = blockIdx.x, tid = threadIdx.x;
    const float* pp = part + (long)b * 14 * 768;
    float a0 = 0.f, a1 = 0.f, a2 = 0.f;
    for (int g = 0; g < 14; g++) {
        a0 += pp[g * 768 + tid]; a1 += pp[g * 768 + tid + 256]; a2 += pp[g * 768 + tid + 512];
    }
    a0 *= (1.f / 196.f); a1 *= (1.f / 196.f); a2 *= (1.f / 196.f);
    float mean = block_reduce_sum(a0 + a1 + a2, sm) * (1.f / 768.f);
    float d0 = a0 - mean, d1 = a1 - mean, d2 = a2 - mean;
    float var = block_reduce_sum(d0 * d0 + d1 * d1 + d2 * d2, sm) * (1.f / 768.f);
    float rs = rsqrtf(var + LN_EPS);
    pooled[(long)b * 768 + tid] = d0 * rs;
    pooled[(long)b * 768 + tid + 256] = d1 * rs;
    pooled[(long)b * 768 + tid + 512] = d2 * rs;
}

// out = pooled @ head_w^T + head_b.  grid (250, 64): wave w -> col 4*bx+w.
__global__ __launch_bounds__(256) void k_head(const float* __restrict__ pooled,
                                              const float* __restrict__ hw,
                                              const float* __restrict__ hb,
                                              float* __restrict__ out) {
    __shared__ float pr[768];
    int b = blockIdx.y, tid = threadIdx.x;
    pr[tid] = pooled[(long)b * 768 + tid];
    pr[tid + 256] = pooled[(long)b * 768 + tid + 256];
    pr[tid + 512] = pooled[(long)b * 768 + tid + 512];
    __syncthreads();
    int c = blockIdx.x * 4 + (tid >> 6);
    int lane = tid & 63;
    const float* wrow = hw + (long)c * 768;
    float acc = 0.f;
    #pragma unroll
    for (int k = 0; k < 768; k += 64) acc += pr[k + lane] * wrow[k + lane];
    #pragma unroll
    for (int o = 32; o; o >>= 1) acc += __shfl_xor(acc, o);
    if (lane == 0) out[(long)b * 1000 + c] = acc + hb[c];
}

// ---------------------------------------------------------------------------
extern "C" void kernel_launch(void* const* d_in, const int* in_sizes, int n_in,
                              void* d_out, int out_size, void* d_ws, size_t ws_size,
                              hipStream_t stream) {
    const float* x     = (const float*)d_in[0];
    const float* convw = (const float*)d_in[1];
    const float* convb = (const float*)d_in[2];
    const float* pe    = (const float*)d_in[3];
    const float* enc   = (const float*)d_in[4];
    const float* encv  = (const float*)d_in[5];
    const float* dec   = (const float*)d_in[6];
    const float* freqs = (const float*)d_in[7];
    const float* hw    = (const float*)d_in[8];
    const float* hbias = (const float*)d_in[9];
    float* out = (float*)d_out;

    char* W = (char*)d_ws;
    size_t off = 0;
    auto ALLOC = [&](size_t bytes) {
        size_t o = off;
        off += (bytes + 255) & ~(size_t)255;
        return o;
    };
    // persistent
    float* bh    = (float*)(W + ALLOC(38535168));            // h f32 (setup only)
    u16*   bhnb  = (u16*)  (W + ALLOC(19267584 + 524288));   // hn bf16 (+edge slack)
    u16*   bhnT  = (u16*)  (W + ALLOC(22020096));            // hn^T bf16 (64,768,224)
    u16*   benc  = (u16*)  (W + ALLOC(9437184));             // enc^T  (12,512,768)
    u16*   bencv = (u16*)  (W + ALLOC(9437184));             // encv^T
    u16*   bdec  = (u16*)  (W + ALLOC(9437184));             // dec^T  (768,6144)
    float* btc   = (float*)(W + ALLOC(401408));              // cos (196,512)
    float* bts   = (float*)(W + ALLOC(401408));              // sin
    float* bpool = (float*)(W + ALLOC(196608));              // pooled (64,768)
    float* bpart = (float*)(W + ALLOC(2752512));             // pool partials (64,14,768)
    float* bstats= (float*)(W + ALLOC(301056));              // ykv row stats (192*196 x f32x2)
    float* bcs   = (float*)(W + ALLOC(24576));               // encv colsums (12,512)
    // chunk regions (+slack for masked edge-tile overreads)
    char*  R1    = (char*) (W + ALLOC(38535168 + 2097152));  // qr / z
    char*  R2    = (char*) (W + ALLOC(57802752 + 524288));   // ykv / rawK (+setup patches)
    char*  R3    = (char*) (W + ALLOC(38535168 + 524288));   // xs (+setup conv_w)
    (void)ws_size; (void)in_sizes; (void)n_in; (void)out_size;

    u16*   bap  = (u16*)R2;    // setup: packed patches (18.4M)
    u16*   bcw  = (u16*)R3;    // setup: conv_w bf16 (1.2M)
    u16*   qr   = (u16*)R1;    // per-chunk head-major (192hb,196,512)
    u16*   z    = (u16*)R1;    // (3136,6144)
    u16*   ykv  = (u16*)R2;    // head-major (192hb,196,768)
    float* rawK = (float*)R2;  // yMLP split-K partials 4x(3136,768) f32
    u16*   xs   = (u16*)R3;    // head-major (192hb,196,512)

    // ---- setup ----
    k_pack_patches<<<37632, 256, 0, stream>>>(x, bap);
    k_cast<<<2304, 256, 0, stream>>>(convw, bcw, 768 * 768);
    k_gemm_tokens<<<dim3(98, 6), 256, 0, stream>>>(bap, bcw, convb, pe, bh);
    k_transpose_cast<<<dim3(16, 24, 12), 256, 0, stream>>>(enc, benc, 768, 512);
    k_transpose_cast<<<dim3(16, 24, 12), 256, 0, stream>>>(encv, bencv, 768, 512);
    k_transpose_cast<<<dim3(24, 192, 1), 256, 0, stream>>>(dec, bdec, 6144, 768);
    k_rope_tab<<<392, 256, 0, stream>>>(freqs, btc, bts);
    k_colsum<<<dim3(2, 12), 256, 0, stream>>>(encv, bcs);
    k_ln1<<<12544, 256, 0, stream>>>(bh, bhnb);   // once; thereafter LN(LN)~id

    // ---- 6 shared-weight layers, 4 chunks of 16 images each ----
    for (int L = 0; L < 6; ++L) {
        k_hnT<<<dim3(7, 24, 64), 256, 0, stream>>>(bhnb, bhnT);
        for (int c = 0; c < 4; ++c) {
            long r0 = (long)c * MC;                    // chunk row offset
            k_gemm_xs<<<dim3(25, 48), 256, 0, stream>>>(
                bhnb + r0 * 768, benc, btc, bts, xs, qr);
            k_attn<<<768, 256, 0, stream>>>(
                qr, bhnT + (long)c * 16 * 768 * 224, ykv, bstats);
            k_gemm_ys<<<dim3(25, 4, 12), 256, 0, stream>>>(ykv, bencv, xs, bstats, bcs, z);
            k_gemm_mlp<<<dim3(25, 6, 4), 256, 0, stream>>>(z, bdec, rawK);
            k_final_h<<<MC, 256, 0, stream>>>(rawK, bhnb + r0 * 768);
        }
    }

    // ---- head ----
    k_pool1<<<dim3(14, 64), 256, 0, stream>>>(bhnb, bpart);
    k_pool2<<<64, 256, 0, stream>>>(bpart, bpool);
    k_head<<<dim3(250, 64), 256, 0, stream>>>(bpool, hw, hbias, out);
}

// Round 11
// 5905.590 us; speedup vs baseline: 1.3263x; 1.0840x over previous
//
#include <hip/hip_runtime.h>
#include <hip/hip_bf16.h>

// ============================================================================
// VisionBDHv2 forward, MI355X (gfx950). Round 18.
// R15: 6049us BEST. R16 (direct loads): 171us attn. R17 (64-row TLP): 105us.
// Synthesis of R11-R17 attn data: time tracks steps-per-block x drain-cost,
// but ONLY when per-step structure matches the proven GEMM cores (8 loads +
// 32 MFMA: ys/xs/mlp run ~2600cyc/step). R13 failed with 12-load steps;
// R17 failed with 16-MFMA steps.
// R18 = R15 geometry (128-row tiles, grid 384, remap) with proven-structure
// BK=64 steps: drains 74 -> 40 at constant staged bytes / LDS / VGPR class:
//   - scores: 2x gemm_core64 (K=512, 8 steps each), LDS aliased in Pl[0:32K]
//   - PV: per cd, 3x BK=64 (core64 row&7 swizzle) + 1x BK=32 tail (R12
//     (row>>1)&3 swizzle); A from Pl stride-232 (2-way alias = free)
//   - LDS = Pl 59.4K + Bl 16K + part 2K = 77824B, byte-identical to R15.
// Everything outside k_attn identical to R15.
// ============================================================================

typedef short bf16x8 __attribute__((ext_vector_type(8)));
typedef float f32x4 __attribute__((ext_vector_type(4)));
typedef unsigned short u16;

#define LN_EPS 1e-5f
#define SM_SCALE 0.044194173824159216f  /* 1/sqrt(512) */
#define TWO_PI 6.283185307179586f
#define MC 3136                          /* rows per chunk = 16*196 */

typedef __attribute__((address_space(3))) unsigned char* as3p;
typedef const __attribute__((address_space(1))) unsigned char* as1p;

__device__ __forceinline__ void gload16(const u16* g, u16* l) {
    __builtin_amdgcn_global_load_lds((as1p)(const void*)g, (as3p)(void*)l, 16, 0, 0);
}

__device__ __forceinline__ u16 f2bf(float f) {
    __hip_bfloat16 h = __float2bfloat16(f);
    return *reinterpret_cast<u16*>(&h);
}
__device__ __forceinline__ float bf2f(u16 u) {
    return __uint_as_float(((unsigned)u) << 16);
}

// ---------------------------------------------------------------------------
// block reductions (256 threads, 4 waves)
// ---------------------------------------------------------------------------
__device__ __forceinline__ float block_reduce_sum(float v, float* sm) {
    #pragma unroll
    for (int o = 32; o; o >>= 1) v += __shfl_xor(v, o);
    if ((threadIdx.x & 63) == 0) sm[threadIdx.x >> 6] = v;
    __syncthreads();
    float r = sm[0] + sm[1] + sm[2] + sm[3];
    __syncthreads();
    return r;
}

// ---------------------------------------------------------------------------
// GEMM core (R7/R11 gemm_core64, verbatim): BK=64, swizzled, 128x128 tile,
// 4 waves (2x2). LDS [128][64] u16 per operand; physical slot s holds
// logical col-slot s^(row&7). Staged via global_load_lds with pre-swizzled
// global source (linear LDS dest). ds_read applies same XOR. C/D: elem i ->
// row (lane>>4)*4+i, col lane&15.
// ---------------------------------------------------------------------------
__device__ __forceinline__ void gemm_core64(const u16* __restrict__ A, int lda,
                                            const u16* __restrict__ Bt, int ldb,
                                            int ksteps, f32x4 acc[4][4],
                                            u16* lds_a, u16* lds_b) {
    const int tid = threadIdx.x;
    const int lane = tid & 63;
    const int wave = tid >> 6;
    const int wr = (wave >> 1) * 64;
    const int wc = (wave & 1) * 64;
    const int lr = lane & 15;
    const int lg = lane >> 4;            // logical k-slot base (0..3)
    const int rx = lr & 7;               // row&7 for this lane's fragment rows
    const int srow = tid >> 3;           // staging row within 32-row group
    const int gslot = (tid & 7) ^ (srow & 7);  // pre-swizzled global col slot
    const u16* ga = A + (long)srow * lda + gslot * 8;
    const u16* gb = Bt + (long)srow * ldb + gslot * 8;
    u16* la = lds_a + tid * 8;           // linear dest: row srow, slot tid&7
    u16* lb = lds_b + tid * 8;
    for (int k0 = 0; k0 < ksteps; ++k0) {
        __syncthreads();                 // prior iteration's reads done
        #pragma unroll
        for (int j = 0; j < 4; ++j) {    // 32-row groups (row&7 invariant)
            gload16(ga + (long)(j * 32) * lda, la + j * 2048);
            gload16(gb + (long)(j * 32) * ldb, lb + j * 2048);
        }
        ga += 64; gb += 64;
        __syncthreads();                 // drains vmcnt(0) before barrier
        bf16x8 af[2][4], bfr[2][4];
        #pragma unroll
        for (int kk = 0; kk < 2; ++kk) {
            const int ps = ((lg + kk * 4) ^ rx) * 8;   // physical elem offset
            #pragma unroll
            for (int m = 0; m < 4; m++)
                af[kk][m] = *(const bf16x8*)&lds_a[(wr + 16 * m + lr) * 64 + ps];
            #pragma unroll
            for (int n = 0; n < 4; n++)
                bfr[kk][n] = *(const bf16x8*)&lds_b[(wc + 16 * n + lr) * 64 + ps];
        }
        #pragma unroll
        for (int kk = 0; kk < 2; ++kk)
            #pragma unroll
            for (int m = 0; m < 4; m++)
                #pragma unroll
                for (int n = 0; n < 4; n++)
                    acc[m][n] = __builtin_amdgcn_mfma_f32_16x16x32_bf16(
                        af[kk][m], bfr[kk][n], acc[m][n], 0, 0, 0);
    }
}

// merged 32KB LDS: gemm uses [lds_a | lds_b]; epilogue reuses as one tile
// (TU u16[128][128] or TF f32[64][128]).
#define GEMM64_PROLOGUE                                 \
    __shared__ alignas(16) u16 lds_ab[2 * 128 * 64];    \
    u16* lds_a = lds_ab;                                \
    u16* lds_b = lds_ab + 128 * 64;                     \
    f32x4 acc[4][4];                                    \
    _Pragma("unroll")                                   \
    for (int m = 0; m < 4; m++)                         \
        _Pragma("unroll")                               \
        for (int n = 0; n < 4; n++)                     \
            acc[m][n] = (f32x4){0.f, 0.f, 0.f, 0.f};

#define EPI_VARS                                        \
    const int lane = threadIdx.x & 63;                  \
    const int wave = threadIdx.x >> 6;                  \
    const int ewr = (wave >> 1) * 64 + (lane >> 4) * 4; \
    const int ewc = (wave & 1) * 64 + (lane & 15);

// ---------------------------------------------------------------------------
// setup kernels
// ---------------------------------------------------------------------------
__global__ __launch_bounds__(256) void k_pack_patches(const float* __restrict__ x,
                                                      u16* __restrict__ ap) {
    int idx = blockIdx.x * 256 + threadIdx.x;           // < 12544*768
    int r = idx / 768, k = idx - r * 768;
    int b = r / 196, t = r - b * 196;
    int hp = t / 14, wp = t - hp * 14;
    int c = k >> 8, rem = k & 255, p = rem >> 4, q = rem & 15;
    long src = ((long)(b * 3 + c) * 224 + hp * 16 + p) * 224 + wp * 16 + q;
    ap[idx] = f2bf(x[src]);
}

__global__ __launch_bounds__(256) void k_cast(const float* __restrict__ s,
                                              u16* __restrict__ d, int n) {
    int i = blockIdx.x * 256 + threadIdx.x;
    if (i < n) d[i] = f2bf(s[i]);
}

// src (batch, R, C) f32 -> dst (batch, C, R) bf16
__global__ __launch_bounds__(256) void k_transpose_cast(const float* __restrict__ src,
                                                        u16* __restrict__ dst,
                                                        int R, int C) {
    __shared__ float tile[32][33];
    int c0 = blockIdx.x * 32, r0 = blockIdx.y * 32;
    long base = (long)blockIdx.z * R * C;
    int i = threadIdx.x >> 5, j = threadIdx.x & 31;
    #pragma unroll
    for (int p = 0; p < 4; p++) {
        int rr = i + p * 8;
        tile[rr][j] = src[base + (long)(r0 + rr) * C + c0 + j];
    }
    __syncthreads();
    #pragma unroll
    for (int p = 0; p < 4; p++) {
        int rr = i + p * 8;
        dst[base + (long)(c0 + rr) * R + r0 + j] = f2bf(tile[j][rr]);
    }
}

__global__ __launch_bounds__(256) void k_rope_tab(const float* __restrict__ freqs,
                                                  float* __restrict__ tc,
                                                  float* __restrict__ ts) {
    int idx = blockIdx.x * 256 + threadIdx.x;           // < 196*512
    int t = idx >> 9, n = idx & 511;
    float ph = (float)t * freqs[n];
    ph = (ph - floorf(ph)) * TWO_PI;
    tc[idx] = cosf(ph);
    ts[idx] = sinf(ph);
}

// colsum[h][c] = sum_d encv[h][d][c]  (from f32 encv, coalesced in c)
__global__ __launch_bounds__(256) void k_colsum(const float* __restrict__ encv,
                                                float* __restrict__ cs) {
    int h = blockIdx.y, c = blockIdx.x * 256 + threadIdx.x;   // grid (2,12)
    const float* base = encv + (long)h * 768 * 512 + c;
    float a = 0.f;
    for (int d = 0; d < 768; d++) a += base[(long)d * 512];
    cs[h * 512 + c] = a;
}

// ---------------------------------------------------------------------------
// GEMM kernels (R11 core + LDS-bounce epilogues)
// ---------------------------------------------------------------------------
// tokens = patches @ convw^T + bias + pos_embed -> h   (M=12544,K=768,N=768)
__global__ __launch_bounds__(256) void k_gemm_tokens(const u16* __restrict__ ap,
                                                     const u16* __restrict__ bw,
                                                     const float* __restrict__ cb,
                                                     const float* __restrict__ pe,
                                                     float* __restrict__ hout) {
    GEMM64_PROLOGUE
    int row0 = blockIdx.x * 128, col0 = blockIdx.y * 128;
    gemm_core64(ap + (long)row0 * 768, 768, bw + (long)col0 * 768, 768, 12, acc, lds_a, lds_b);
    EPI_VARS
    const int tid = threadIdx.x;
    float* TF = (float*)lds_ab;          // [64][128] f32, two half-passes
    #pragma unroll
    for (int hf = 0; hf < 2; ++hf) {
        __syncthreads();
        if ((ewr >> 6) == hf) {
            #pragma unroll
            for (int m = 0; m < 4; m++)
                #pragma unroll
                for (int n = 0; n < 4; n++)
                    #pragma unroll
                    for (int i = 0; i < 4; i++) {
                        int row = row0 + ewr + 16 * m + i;
                        int col = col0 + ewc + 16 * n;
                        int t = row % 196;
                        TF[(ewr - hf * 64 + 16 * m + i) * 128 + ewc + 16 * n] =
                            acc[m][n][i] + cb[col] + pe[t * 768 + col];
                    }
        }
        __syncthreads();
        #pragma unroll
        for (int q = 0; q < 8; ++q) {
            int chunk = tid + q * 256;   // 64 rows x 32 chunks (16B=4 f32)
            int r = chunk >> 5, c = chunk & 31;
            *(f32x4*)&hout[(long)(row0 + hf * 64 + r) * 768 + col0 + c * 4] =
                *(f32x4*)&TF[r * 128 + c * 4];
        }
    }
}

// chunk: x_sparse = relu(hn@enc); qr = rope(x_sparse)  (M=3136 masked, N=6144)
// xs/qr written HEAD-MAJOR: [(head*16+bL)*196 + t][512]
// R15: rope pass vectorized (TU readback + f32x4 tables + in-reg pair rotate)
__global__ __launch_bounds__(256) void k_gemm_xs(const u16* __restrict__ hnb,
                                                 const u16* __restrict__ enct,
                                                 const float* __restrict__ tc,
                                                 const float* __restrict__ tsn,
                                                 u16* __restrict__ xs,
                                                 u16* __restrict__ qr) {
    GEMM64_PROLOGUE
    // XCD swizzle: grid (25,48) -> 1200 wgs, q=150
    int p = blockIdx.x + 25 * blockIdx.y;
    int w = (p & 7) * 150 + (p >> 3);
    int row0 = (w % 25) * 128, col0 = (w / 25) * 128;
    int head = col0 >> 9, nn0 = col0 & 511;
    gemm_core64(hnb + (long)row0 * 768, 768,
                enct + ((long)head * 512 + nn0) * 768, 768, 12, acc, lds_a, lds_b);
    EPI_VARS
    const int tid = threadIdx.x;
    u16* TU = lds_ab;                    // [128][128] u16
    // ---- pass 1: xs = relu(acc) -> TU -> vector store ----
    __syncthreads();
    #pragma unroll
    for (int m = 0; m < 4; m++)
        #pragma unroll
        for (int n = 0; n < 4; n++)
            #pragma unroll
            for (int i = 0; i < 4; i++)
                TU[(ewr + 16 * m + i) * 128 + ewc + 16 * n] =
                    f2bf(fmaxf(acc[m][n][i], 0.f));
    __syncthreads();
    #pragma unroll
    for (int q = 0; q < 8; ++q) {
        int chunk = tid + q * 256;       // 128 rows x 16 chunks (16B=8 u16)
        int r = chunk >> 4, c = chunk & 15;
        int row = row0 + r;
        if (row < MC)
            *(bf16x8*)&xs[((long)head * MC + row) * 512 + nn0 + c * 8] =
                *(bf16x8*)&TU[r * 128 + c * 8];
    }
    // ---- pass 2: qr = rope(TU) -- reads TU only, vectorized tables ----
    #pragma unroll
    for (int q = 0; q < 8; ++q) {
        int chunk = tid + q * 256;
        int r = chunk >> 4, c = chunk & 15;
        int row = row0 + r;
        if (row < MC) {
            int t = row % 196;
            int nn = nn0 + c * 8;
            bf16x8 v8 = *(bf16x8*)&TU[r * 128 + c * 8];
            f32x4 cs0 = *(const f32x4*)&tc[t * 512 + nn];
            f32x4 cs1 = *(const f32x4*)&tc[t * 512 + nn + 4];
            f32x4 sn0 = *(const f32x4*)&tsn[t * 512 + nn];
            f32x4 sn1 = *(const f32x4*)&tsn[t * 512 + nn + 4];
            float v[8], qv[8];
            #pragma unroll
            for (int j = 0; j < 8; j++) v[j] = bf2f((u16)v8[j]);
            #pragma unroll
            for (int j = 0; j < 2; j++) {
                qv[2 * j]     = v[2 * j] * cs0[2 * j]     - v[2 * j + 1] * sn0[2 * j];
                qv[2 * j + 1] = v[2 * j + 1] * cs0[2 * j + 1] + v[2 * j] * sn0[2 * j + 1];
                qv[4 + 2 * j]     = v[4 + 2 * j] * cs1[2 * j]     - v[4 + 2 * j + 1] * sn1[2 * j];
                qv[4 + 2 * j + 1] = v[4 + 2 * j + 1] * cs1[2 * j + 1] + v[4 + 2 * j] * sn1[2 * j + 1];
            }
            bf16x8 o8;
            #pragma unroll
            for (int j = 0; j < 8; j++) o8[j] = (short)f2bf(qv[j]);
            *(bf16x8*)&qr[((long)head * MC + row) * 512 + nn] = o8;
        }
    }
}

// ---------------------------------------------------------------------------
// Fused attention + ykv row stats (mu, rs) for the ys LN-fold.
// R18: R15 geometry (128-row tiles, grid 384, XCD/bL remap) with BK=64
// proven-structure steps: scores = 2x gemm_core64 (LDS aliased in Pl[0:32K]);
// PV = per cd 3x BK=64 (row&7 swizzle) + 1x BK=32 tail ((row>>1)&3 swizzle).
// Drain-steps/block: 40 (was 74). LDS: Pl 59.4K + Bl 16K + part 2K = 77824B.
// ---------------------------------------------------------------------------
__global__ __launch_bounds__(256) void k_attn(const u16* __restrict__ qr,
                                              const u16* __restrict__ hnT,
                                              u16* __restrict__ ykv,
                                              float* __restrict__ stats) {
    __shared__ alignas(16) u16 Pl[128 * 232];   // [0:16Ku16) aliased by scores
    __shared__ alignas(16) u16 Bl[128 * 64];    // PV B tile (16KB)
    __shared__ float part[2][128][2];    // [max|sum][row][wave-col-half]
    const int tid = threadIdx.x, lane = tid & 63, wave = tid >> 6;
    const int wr = (wave >> 1) * 64, wc = (wave & 1) * 64;
    const int lr = lane & 15, lg = lane >> 4, lk = lg * 8;
    const int rx = lr & 7;
    // XCD/bL-locality remap (bijective over 384)
    const int p = blockIdx.x;            // 0..383
    const int xcd = p & 7, slot = p >> 3;          // 8 x 48
    const int bL = 2 * xcd + (slot >= 24);
    const int sub = (slot >= 24) ? slot - 24 : slot;   // 0..23
    const int h = sub >> 1, rt = sub & 1;
    const int bh = h * 16 + bL;
    const int row0 = rt * 128;
    const u16* qbase = qr + (long)bh * 196 * 512;

    f32x4 acc0[4][4], acc1[4][4];
    #pragma unroll
    for (int m = 0; m < 4; m++)
        #pragma unroll
        for (int n = 0; n < 4; n++) {
            acc0[m][n] = (f32x4){0.f, 0.f, 0.f, 0.f};
            acc1[m][n] = (f32x4){0.f, 0.f, 0.f, 0.f};
        }
    // ---- scores: S[row,col] = Q[row0+row].Q[col], two 128-col tiles, K=512,
    //      BK=64 core (8 steps/call). LDS aliased into Pl[0:32KB). ----
    {
        u16* sA = Pl;
        u16* sB = Pl + 128 * 64;
        gemm_core64(qbase + (long)row0 * 512, 512, qbase, 512, 8, acc0, sA, sB);
        gemm_core64(qbase + (long)row0 * 512, 512, qbase + 128 * 512, 512, 8, acc1, sA, sB);
    }

    // ---- softmax over cols (valid < 196), scale applied inside exp ----
    const int rb = wr + (lane >> 4) * 4;
    #pragma unroll
    for (int m = 0; m < 4; m++)
        #pragma unroll
        for (int i = 0; i < 4; i++) {
            float mx = -1e30f;
            #pragma unroll
            for (int n = 0; n < 4; n++) {
                int c0 = wc + 16 * n + lr;
                if (c0 < 196) mx = fmaxf(mx, acc0[m][n][i]);
                if (c0 + 128 < 196) mx = fmaxf(mx, acc1[m][n][i]);
            }
            #pragma unroll
            for (int o = 1; o < 16; o <<= 1) mx = fmaxf(mx, __shfl_xor(mx, o));
            if (lr == 0) part[0][rb + 16 * m + i][wave & 1] = mx;
        }
    __syncthreads();      // also orders last scores LDS reads before Pl writes
    #pragma unroll
    for (int m = 0; m < 4; m++)
        #pragma unroll
        for (int i = 0; i < 4; i++) {
            int row = rb + 16 * m + i;
            float rmx = fmaxf(part[0][row][0], part[0][row][1]);
            float s = 0.f;
            #pragma unroll
            for (int n = 0; n < 4; n++) {
                int c0 = wc + 16 * n + lr;
                float e0 = (c0 < 196) ? __expf((acc0[m][n][i] - rmx) * SM_SCALE) : 0.f;
                float e1 = (c0 + 128 < 196) ? __expf((acc1[m][n][i] - rmx) * SM_SCALE) : 0.f;
                acc0[m][n][i] = e0; acc1[m][n][i] = e1;
                s += e0 + e1;
            }
            #pragma unroll
            for (int o = 1; o < 16; o <<= 1) s += __shfl_xor(s, o);
            if (lr == 0) part[1][row][wave & 1] = s;
        }
    __syncthreads();
    #pragma unroll
    for (int m = 0; m < 4; m++)
        #pragma unroll
        for (int i = 0; i < 4; i++) {
            int row = rb + 16 * m + i;
            float inv = 1.f / (part[1][row][0] + part[1][row][1]);
            #pragma unroll
            for (int n = 0; n < 4; n++) {
                int c0 = wc + 16 * n + lr;
                Pl[row * 232 + c0] = f2bf(acc0[m][n][i] * inv);
                if (c0 + 128 < 224)
                    Pl[row * 232 + c0 + 128] = f2bf(acc1[m][n][i] * inv);
            }
        }
    __syncthreads();                      // Pl visible
    // part[] now free: zero it for ykv row-stats accumulation
    { float* pf = &part[0][0][0]; pf[tid] = 0.f; pf[tid + 256] = 0.f; }
    __syncthreads();

    // ---- PV: O[row,d] = sum_s P[row,s]*hnT[d][s]; 6 cd slabs, K=224 ----
    // per cd: 3x BK=64 steps + 1x BK=32 tail. B staged swizzled into Bl.
    const int srow8 = tid >> 3;                    // 0..31
    const int gsl8 = (tid & 7) ^ (srow8 & 7);
    const int srow2 = tid >> 2;                    // 0..63
    const int gsl2 = (tid & 3) ^ ((srow2 >> 1) & 3);
    const int ps32 = (lg ^ ((lr >> 1) & 3)) * 8;
    const u16* hbase = hnT + (long)bL * 768 * 224;
    for (int cd = 0; cd < 6; ++cd) {
        const u16* Bt = hbase + (long)(cd * 128) * 224;
        f32x4 pacc[4][4];
        #pragma unroll
        for (int m = 0; m < 4; m++)
            #pragma unroll
            for (int n = 0; n < 4; n++) pacc[m][n] = (f32x4){0.f, 0.f, 0.f, 0.f};
        // 3 BK=64 steps (k = 0, 64, 128)
        for (int k0 = 0; k0 < 3; ++k0) {
            __syncthreads();             // prior step's Bl reads done
            #pragma unroll
            for (int j = 0; j < 4; ++j)
                gload16(Bt + (long)(j * 32 + srow8) * 224 + k0 * 64 + gsl8 * 8,
                        Bl + j * 2048 + tid * 8);
            __syncthreads();             // drain
            bf16x8 af[2][4], bfr[2][4];
            #pragma unroll
            for (int kk = 0; kk < 2; ++kk) {
                const int ps = ((lg + 4 * kk) ^ rx) * 8;
                #pragma unroll
                for (int m = 0; m < 4; m++)
                    af[kk][m] = *(const bf16x8*)&Pl[(wr + 16 * m + lr) * 232 +
                                                    k0 * 64 + kk * 32 + lk];
                #pragma unroll
                for (int n = 0; n < 4; n++)
                    bfr[kk][n] = *(const bf16x8*)&Bl[(wc + 16 * n + lr) * 64 + ps];
            }
            #pragma unroll
            for (int kk = 0; kk < 2; ++kk)
                #pragma unroll
                for (int m = 0; m < 4; m++)
                    #pragma unroll
                    for (int n = 0; n < 4; n++)
                        pacc[m][n] = __builtin_amdgcn_mfma_f32_16x16x32_bf16(
                            af[kk][m], bfr[kk][n], pacc[m][n], 0, 0, 0);
        }
        // BK=32 tail (k = 192..223)
        {
            __syncthreads();
            gload16(Bt + (long)srow2 * 224 + 192 + gsl2 * 8, Bl + tid * 8);
            gload16(Bt + (long)(srow2 + 64) * 224 + 192 + gsl2 * 8, Bl + 2048 + tid * 8);
            __syncthreads();
            bf16x8 af[4], bfr[4];
            #pragma unroll
            for (int m = 0; m < 4; m++)
                af[m] = *(const bf16x8*)&Pl[(wr + 16 * m + lr) * 232 + 192 + lk];
            #pragma unroll
            for (int n = 0; n < 4; n++)
                bfr[n] = *(const bf16x8*)&Bl[(wc + 16 * n + lr) * 32 + ps32];
            #pragma unroll
            for (int m = 0; m < 4; m++)
                #pragma unroll
                for (int n = 0; n < 4; n++)
                    pacc[m][n] = __builtin_amdgcn_mfma_f32_16x16x32_bf16(
                        af[m], bfr[n], pacc[m][n], 0, 0, 0);
        }
        // row-stats partials for this 128-col slab (per-thread slots, no race)
        #pragma unroll
        for (int m = 0; m < 4; m++)
            #pragma unroll
            for (int i = 0; i < 4; i++) {
                float s = pacc[m][0][i] + pacc[m][1][i] + pacc[m][2][i] + pacc[m][3][i];
                float q2 = pacc[m][0][i] * pacc[m][0][i] + pacc[m][1][i] * pacc[m][1][i] +
                           pacc[m][2][i] * pacc[m][2][i] + pacc[m][3][i] * pacc[m][3][i];
                #pragma unroll
                for (int o = 1; o < 16; o <<= 1) {
                    s += __shfl_xor(s, o);
                    q2 += __shfl_xor(q2, o);
                }
                if (lr == 0) {
                    part[0][rb + 16 * m + i][wave & 1] += s;
                    part[1][rb + 16 * m + i][wave & 1] += q2;
                }
            }
        // epilogue: store this d-slab
        {
            const int ewr = wr + (lane >> 4) * 4;
            const int ewc = wc + lr;
            #pragma unroll
            for (int m = 0; m < 4; m++)
                #pragma unroll
                for (int n = 0; n < 4; n++)
                    #pragma unroll
                    for (int i = 0; i < 4; i++) {
                        int trow = row0 + ewr + 16 * m + i;
                        if (trow < 196)
                            ykv[((long)bh * 196 + trow) * 768 + cd * 128 + ewc + 16 * n] =
                                f2bf(pacc[m][n][i]);
                    }
        }
    }
    // finalize row stats
    __syncthreads();
    if (tid < 128) {
        int trow = row0 + tid;
        if (trow < 196) {
            float s = part[0][tid][0] + part[0][tid][1];
            float q2 = part[1][tid][0] + part[1][tid][1];
            float mu = s * (1.f / 768.f);
            float var = q2 * (1.f / 768.f) - mu * mu;
            float2 st;
            st.x = mu;
            st.y = rsqrtf(var + LN_EPS);
            *(float2*)&stats[((long)bh * 196 + trow) * 2] = st;
        }
    }
}

// y_sparse = relu(LN(ykv) @ encv) via fold: rs*(acc - mu*colsum);
// z = x_sparse*y_sparse, head-major flatten. grid (25,4,12), swizzled.
__global__ __launch_bounds__(256) void k_gemm_ys(const u16* __restrict__ ykv,
                                                 const u16* __restrict__ encvt,
                                                 const u16* __restrict__ xs,
                                                 const float* __restrict__ stats,
                                                 const float* __restrict__ colsum,
                                                 u16* __restrict__ z) {
    GEMM64_PROLOGUE
    // XCD swizzle: 1200 wgs, q=150
    int p = blockIdx.x + 25 * (blockIdx.y + 4 * blockIdx.z);
    int w = (p & 7) * 150 + (p >> 3);
    int rt = w % 25, rem = w / 25;
    int ct = rem & 3, h = rem >> 2;
    int row0 = rt * 128, col0 = ct * 128;
    gemm_core64(ykv + ((long)h * MC + row0) * 768, 768,
                encvt + ((long)h * 512 + col0) * 768, 768, 12, acc, lds_a, lds_b);
    EPI_VARS
    const int tid = threadIdx.x;
    u16* TU = lds_ab;                    // [128][128]
    // phase A: vector-load xs tile
    __syncthreads();
    #pragma unroll
    for (int q = 0; q < 8; ++q) {
        int chunk = tid + q * 256;
        int r = chunk >> 4, c = chunk & 15;
        *(bf16x8*)&TU[r * 128 + c * 8] =
            *(const bf16x8*)&xs[((long)h * MC + row0 + r) * 512 + col0 + c * 8];
    }
    __syncthreads();
    // phase B: in-place fold+relu+mul (thread-owned slots)
    #pragma unroll
    for (int m = 0; m < 4; m++)
        #pragma unroll
        for (int i = 0; i < 4; i++) {
            int rloc = ewr + 16 * m + i;
            int row = row0 + rloc;
            float mu = 0.f, rs = 0.f;
            if (row < MC) {
                float2 st = *(const float2*)&stats[((long)h * MC + row) * 2];
                mu = st.x; rs = st.y;
            }
            #pragma unroll
            for (int n = 0; n < 4; n++) {
                int cloc = ewc + 16 * n;
                float cs = colsum[h * 512 + col0 + cloc];
                float v = (acc[m][n][i] - mu * cs) * rs;
                v = fmaxf(v, 0.f) * bf2f(TU[rloc * 128 + cloc]);
                TU[rloc * 128 + cloc] = f2bf(v);
            }
        }
    __syncthreads();
    // phase C: vector-store z tile
    #pragma unroll
    for (int q = 0; q < 8; ++q) {
        int chunk = tid + q * 256;
        int r = chunk >> 4, c = chunk & 15;
        int row = row0 + r;
        if (row < MC)
            *(bf16x8*)&z[(long)row * 6144 + h * 512 + col0 + c * 8] =
                *(bf16x8*)&TU[r * 128 + c * 8];
    }
}

// yMLP_raw partial s = z[:, s*1536:(s+1)*1536] @ dec[s...]  (split-K4)
__global__ __launch_bounds__(256) void k_gemm_mlp(const u16* __restrict__ z,
                                                  const u16* __restrict__ dect,
                                                  float* __restrict__ rawK) {
    GEMM64_PROLOGUE
    // XCD swizzle: grid (25,6,4) -> 600 wgs, q=75
    int p = blockIdx.x + 25 * (blockIdx.y + 6 * blockIdx.z);
    int w = (p & 7) * 75 + (p >> 3);
    int row0 = (w % 25) * 128, col0 = ((w / 25) % 6) * 128, s = w / 150;
    gemm_core64(z + (long)row0 * 6144 + s * 1536, 6144,
                dect + (long)col0 * 6144 + s * 1536, 6144, 24, acc, lds_a, lds_b);
    EPI_VARS
    const int tid = threadIdx.x;
    float* TF = (float*)lds_ab;          // [64][128] f32, two half-passes
    float* raw = rawK + (long)s * MC * 768;
    #pragma unroll
    for (int hf = 0; hf < 2; ++hf) {
        __syncthreads();
        if ((ewr >> 6) == hf) {
            #pragma unroll
            for (int m = 0; m < 4; m++)
                #pragma unroll
                for (int n = 0; n < 4; n++)
                    #pragma unroll
                    for (int i = 0; i < 4; i++)
                        TF[(ewr - hf * 64 + 16 * m + i) * 128 + ewc + 16 * n] =
                            acc[m][n][i];
        }
        __syncthreads();
        #pragma unroll
        for (int q = 0; q < 8; ++q) {
            int chunk = tid + q * 256;
            int r = chunk >> 5, c = chunk & 31;
            int row = row0 + hf * 64 + r;
            if (row < MC)
                *(f32x4*)&raw[(long)row * 768 + col0 + c * 4] =
                    *(f32x4*)&TF[r * 128 + c * 4];
        }
    }
}

// ---------------------------------------------------------------------------
// per-row LN kernels
// ---------------------------------------------------------------------------
// hn = LN(h) -> hn bf16 (used ONCE after tokens; later layers skip: LN(LN)~id)
__global__ __launch_bounds__(256) void k_ln1(const float* __restrict__ h,
                                             u16* __restrict__ hnb) {
    __shared__ float sm[4];
    int r = blockIdx.x, tid = threadIdx.x;
    const float* p = h + (long)r * 768;
    float x0 = p[tid], x1 = p[tid + 256], x2 = p[tid + 512];
    float mean = block_reduce_sum(x0 + x1 + x2, sm) * (1.f / 768.f);
    float d0 = x0 - mean, d1 = x1 - mean, d2 = x2 - mean;
    float var = block_reduce_sum(d0 * d0 + d1 * d1 + d2 * d2, sm) * (1.f / 768.f);
    float rs = rsqrtf(var + LN_EPS);
    long ro = (long)r * 768;
    hnb[ro + tid] = f2bf(d0 * rs);
    hnb[ro + tid + 256] = f2bf(d1 * rs);
    hnb[ro + tid + 512] = f2bf(d2 * rs);
}

// hnT[b][d][tpad224] = hnb[b*196+t][d], t-pad zero-filled. 32x32 LDS tiles.
__global__ __launch_bounds__(256) void k_hnT(const u16* __restrict__ hnb,
                                             u16* __restrict__ hnT) {
    __shared__ u16 tile[32][33];
    int t0 = blockIdx.x * 32, d0 = blockIdx.y * 32, b = blockIdx.z;
    int i = threadIdx.x >> 5, j = threadIdx.x & 31;
    #pragma unroll
    for (int p = 0; p < 4; p++) {
        int t = t0 + i + p * 8;
        tile[i + p * 8][j] = (t < 196) ? hnb[((long)b * 196 + t) * 768 + d0 + j] : (u16)0;
    }
    __syncthreads();
    #pragma unroll
    for (int p = 0; p < 4; p++) {
        int dd = i + p * 8;
        hnT[((long)b * 768 + d0 + dd) * 224 + t0 + j] = tile[j][dd];
    }
}

// hnb = LN(hnb + LN(sum of 4 split-K partials))  [in-place: reads first]
__global__ __launch_bounds__(256) void k_final_h(const float* __restrict__ rawK,
                                                 u16* __restrict__ hnb) {
    __shared__ float sm[4];
    const long PS = (long)MC * 768;
    int r = blockIdx.x, tid = threadIdx.x;
    const float* rp = rawK + (long)r * 768;
    u16* hp = hnb + (long)r * 768;
    float y0 = rp[tid] + rp[tid + PS] + rp[tid + 2 * PS] + rp[tid + 3 * PS];
    float y1 = rp[tid + 256] + rp[tid + 256 + PS] + rp[tid + 256 + 2 * PS] + rp[tid + 256 + 3 * PS];
    float y2 = rp[tid + 512] + rp[tid + 512 + PS] + rp[tid + 512 + 2 * PS] + rp[tid + 512 + 3 * PS];
    float h0 = bf2f(hp[tid]), h1 = bf2f(hp[tid + 256]), h2 = bf2f(hp[tid + 512]);
    float mean = block_reduce_sum(y0 + y1 + y2, sm) * (1.f / 768.f);
    float d0 = y0 - mean, d1 = y1 - mean, d2 = y2 - mean;
    float var = block_reduce_sum(d0 * d0 + d1 * d1 + d2 * d2, sm) * (1.f / 768.f);
    float rs = rsqrtf(var + LN_EPS);
    float s0 = h0 + d0 * rs;
    float s1 = h1 + d1 * rs;
    float s2 = h2 + d2 * rs;
    mean = block_reduce_sum(s0 + s1 + s2, sm) * (1.f / 768.f);
    d0 = s0 - mean; d1 = s1 - mean; d2 = s2 - mean;
    var = block_reduce_sum(d0 * d0 + d1 * d1 + d2 * d2, sm) * (1.f / 768.f);
    rs = rsqrtf(var + LN_EPS);
    hp[tid] = f2bf(d0 * rs);
    hp[tid + 256] = f2bf(d1 * rs);
    hp[tid + 512] = f2bf(d2 * rs);
}

// pool stage 1: partial sums over 14-row groups -> part[b][g][768] (bf16 in)
__global__ __launch_bounds__(256) void k_pool1(const u16* __restrict__ hnb,
                                               float* __restrict__ part) {
    int g = blockIdx.x, b = blockIdx.y, tid = threadIdx.x;
    const u16* base = hnb + ((long)b * 196 + g * 14) * 768;
    float a0 = 0.f, a1 = 0.f, a2 = 0.f;
    for (int t = 0; t < 14; t++) {
        const u16* p = base + (long)t * 768;
        a0 += bf2f(p[tid]); a1 += bf2f(p[tid + 256]); a2 += bf2f(p[tid + 512]);
    }
    float* pp = part + ((long)b * 14 + g) * 768;
    pp[tid] = a0; pp[tid + 256] = a1; pp[tid + 512] = a2;
}

// pool stage 2: pooled = LN(sum(part)/196)
__global__ __launch_bounds__(256) void k_pool2(const float* __restrict__ part,
                                               float* __restrict__ pooled) {
    __shared__ float sm[4];
    int b = blockIdx.x, tid = threadIdx.x;
    const float* pp = part + (long)b * 14 * 768;
    float a0 = 0.f, a1 = 0.f, a2 = 0.f;
    for (int g = 0; g < 14; g++) {
        a0 += pp[g * 768 + tid]; a1 += pp[g * 768 + tid + 256]; a2 += pp[g * 768 + tid + 512];
    }
    a0 *= (1.f / 196.f); a1 *= (1.f / 196.f); a2 *= (1.f / 196.f);
    float mean = block_reduce_sum(a0 + a1 + a2, sm) * (1.f / 768.f);
    float d0 = a0 - mean, d1 = a1 - mean, d2 = a2 - mean;
    float var = block_reduce_sum(d0 * d0 + d1 * d1 + d2 * d2, sm) * (1.f / 768.f);
    float rs = rsqrtf(var + LN_EPS);
    pooled[(long)b * 768 + tid] = d0 * rs;
    pooled[(long)b * 768 + tid + 256] = d1 * rs;
    pooled[(long)b * 768 + tid + 512] = d2 * rs;
}

// out = pooled @ head_w^T + head_b.  grid (250, 64): wave w -> col 4*bx+w.
__global__ __launch_bounds__(256) void k_head(const float* __restrict__ pooled,
                                              const float* __restrict__ hw,
                                              const float* __restrict__ hb,
                                              float* __restrict__ out) {
    __shared__ float pr[768];
    int b = blockIdx.y, tid = threadIdx.x;
    pr[tid] = pooled[(long)b * 768 + tid];
    pr[tid + 256] = pooled[(long)b * 768 + tid + 256];
    pr[tid + 512] = pooled[(long)b * 768 + tid + 512];
    __syncthreads();
    int c = blockIdx.x * 4 + (tid >> 6);
    int lane = tid & 63;
    const float* wrow = hw + (long)c * 768;
    float acc = 0.f;
    #pragma unroll
    for (int k = 0; k < 768; k += 64) acc += pr[k + lane] * wrow[k + lane];
    #pragma unroll
    for (int o = 32; o; o >>= 1) acc += __shfl_xor(acc, o);
    if (lane == 0) out[(long)b * 1000 + c] = acc + hb[c];
}

// ---------------------------------------------------------------------------
extern "C" void kernel_launch(void* const* d_in, const int* in_sizes, int n_in,
                              void* d_out, int out_size, void* d_ws, size_t ws_size,
                              hipStream_t stream) {
    const float* x     = (const float*)d_in[0];
    const float* convw = (const float*)d_in[1];
    const float* convb = (const float*)d_in[2];
    const float* pe    = (const float*)d_in[3];
    const float* enc   = (const float*)d_in[4];
    const float* encv  = (const float*)d_in[5];
    const float* dec   = (const float*)d_in[6];
    const float* freqs = (const float*)d_in[7];
    const float* hw    = (const float*)d_in[8];
    const float* hbias = (const float*)d_in[9];
    float* out = (float*)d_out;

    char* W = (char*)d_ws;
    size_t off = 0;
    auto ALLOC = [&](size_t bytes) {
        size_t o = off;
        off += (bytes + 255) & ~(size_t)255;
        return o;
    };
    // persistent
    float* bh    = (float*)(W + ALLOC(38535168));            // h f32 (setup only)
    u16*   bhnb  = (u16*)  (W + ALLOC(19267584 + 524288));   // hn bf16 (+edge slack)
    u16*   bhnT  = (u16*)  (W + ALLOC(22020096));            // hn^T bf16 (64,768,224)
    u16*   benc  = (u16*)  (W + ALLOC(9437184));             // enc^T  (12,512,768)
    u16*   bencv = (u16*)  (W + ALLOC(9437184));             // encv^T
    u16*   bdec  = (u16*)  (W + ALLOC(9437184));             // dec^T  (768,6144)
    float* btc   = (float*)(W + ALLOC(401408));              // cos (196,512)
    float* bts   = (float*)(W + ALLOC(401408));              // sin
    float* bpool = (float*)(W + ALLOC(196608));              // pooled (64,768)
    float* bpart = (float*)(W + ALLOC(2752512));             // pool partials (64,14,768)
    float* bstats= (float*)(W + ALLOC(301056));              // ykv row stats (192*196 x f32x2)
    float* bcs   = (float*)(W + ALLOC(24576));               // encv colsums (12,512)
    // chunk regions (+slack for masked edge-tile overreads)
    char*  R1    = (char*) (W + ALLOC(38535168 + 2097152));  // qr / z
    char*  R2    = (char*) (W + ALLOC(57802752 + 524288));   // ykv / rawK (+setup patches)
    char*  R3    = (char*) (W + ALLOC(38535168 + 524288));   // xs (+setup conv_w)
    (void)ws_size; (void)in_sizes; (void)n_in; (void)out_size;

    u16*   bap  = (u16*)R2;    // setup: packed patches (18.4M)
    u16*   bcw  = (u16*)R3;    // setup: conv_w bf16 (1.2M)
    u16*   qr   = (u16*)R1;    // per-chunk head-major (192hb,196,512)
    u16*   z    = (u16*)R1;    // (3136,6144)
    u16*   ykv  = (u16*)R2;    // head-major (192hb,196,768)
    float* rawK = (float*)R2;  // yMLP split-K partials 4x(3136,768) f32
    u16*   xs   = (u16*)R3;    // head-major (192hb,196,512)

    // ---- setup ----
    k_pack_patches<<<37632, 256, 0, stream>>>(x, bap);
    k_cast<<<2304, 256, 0, stream>>>(convw, bcw, 768 * 768);
    k_gemm_tokens<<<dim3(98, 6), 256, 0, stream>>>(bap, bcw, convb, pe, bh);
    k_transpose_cast<<<dim3(16, 24, 12), 256, 0, stream>>>(enc, benc, 768, 512);
    k_transpose_cast<<<dim3(16, 24, 12), 256, 0, stream>>>(encv, bencv, 768, 512);
    k_transpose_cast<<<dim3(24, 192, 1), 256, 0, stream>>>(dec, bdec, 6144, 768);
    k_rope_tab<<<392, 256, 0, stream>>>(freqs, btc, bts);
    k_colsum<<<dim3(2, 12), 256, 0, stream>>>(encv, bcs);
    k_ln1<<<12544, 256, 0, stream>>>(bh, bhnb);   // once; thereafter LN(LN)~id

    // ---- 6 shared-weight layers, 4 chunks of 16 images each ----
    for (int L = 0; L < 6; ++L) {
        k_hnT<<<dim3(7, 24, 64), 256, 0, stream>>>(bhnb, bhnT);
        for (int c = 0; c < 4; ++c) {
            long r0 = (long)c * MC;                    // chunk row offset
            k_gemm_xs<<<dim3(25, 48), 256, 0, stream>>>(
                bhnb + r0 * 768, benc, btc, bts, xs, qr);
            k_attn<<<384, 256, 0, stream>>>(
                qr, bhnT + (long)c * 16 * 768 * 224, ykv, bstats);
            k_gemm_ys<<<dim3(25, 4, 12), 256, 0, stream>>>(ykv, bencv, xs, bstats, bcs, z);
            k_gemm_mlp<<<dim3(25, 6, 4), 256, 0, stream>>>(z, bdec, rawK);
            k_final_h<<<MC, 256, 0, stream>>>(rawK, bhnb + r0 * 768);
        }
    }

    // ---- head ----
    k_pool1<<<dim3(14, 64), 256, 0, stream>>>(bhnb, bpart);
    k_pool2<<<64, 256, 0, stream>>>(bpart, bpool);
    k_head<<<dim3(250, 64), 256, 0, stream>>>(bpool, hw, hbias, out);
}